// Round 1
// baseline (740.889 us; speedup 1.0000x reference)
//
#include <hip/hip_runtime.h>
#include <math.h>

#define NP 16384
#define DD 192
#define NS 16
#define KSPN 16
#define MTOT (NP*NS)

typedef unsigned short ushort_t;
typedef __attribute__((ext_vector_type(8))) short short8;
typedef __attribute__((ext_vector_type(4))) float f32x4;

__device__ __forceinline__ ushort_t f2bf(float f) {
    union { float f; unsigned int u; } v; v.f = f;
    return (ushort_t)((v.u + 0x7FFFu + ((v.u >> 16) & 1u)) >> 16);
}
__device__ __forceinline__ float bf2f(ushort_t u) {
    return __uint_as_float(((unsigned int)u) << 16);
}

// ws float offsets
#define WS_KNN   0                         // NP*48   knn_xyz
#define WS_PR    (WS_KNN + NP*48)          // MTOT*3  p_r per window row
#define WS_GEO9  (WS_PR + MTOT*3)          // NP*9
#define WS_GDIS  (WS_GEO9 + NP*9)          // NP
// STATS: [0]=dsum [1]=dmax(bits) [2..50)=sumX [50..2354)=A1 [2354..2498)=A2
//        [2498..2507)=A3 [2507..2510)=sumS
#define WS_STATS (WS_GDIS + NP)
#define WS_VOLV  (WS_STATS + 2512)         // 192
#define WS_AB    (WS_VOLV + DD)            // a[3][192] | bb[3][192] = 1152
#define WS_X1    (WS_AB + 1152)            // NP*192 post-propagate (consumed by k3a)
#define WS_U     (WS_X1 + NP*DD)           // NP*192: CTRB (bf16) after fused attn
#define WS_X2    (WS_U + NP*DD)            // NP*192: X2B (bf16, written by fus gemm)
#define WS_QKV   (WS_X2 + NP*DD)           // NP*576 bf16 (uses half the region)
#define WS_SC    (WS_QKV + NP*576)         // region: XB overlay (bf16 x)
#define WS_ATTN  (WS_SC + NP*DD)           // region: UB overlay (bf16 U)
#define WS_W2T   (WS_ATTN + NP*96)         // 192*192 transposed posW2[2] fp32
#define WS_PROPWT (WS_W2T + 36864)         // 18432 floats (bf16 transposed propW[:192])
#define WS_QKVT  (WS_PROPWT + 18432)       // 55296
#define WS_FUSWT (WS_QKVT + 55296)         // 18432
#define WS_PROJWT (WS_FUSWT + 18432)       // 18432
#define WS_W1T   (WS_PROJWT + 18432)       // 3*192*64 bf16 = 18432 floats (K pad 64)
#define WS_DEW2T (WS_W1T + 18432)          // 192*64 bf16 = 6144 floats (deW2 transposed, K pad 64)
// overlays (bf16 arrays in dead-interval regions):
#define WS_XB    WS_SC
#define WS_UB    WS_ATTN
#define WS_X2B   WS_X2
#define WS_CTRB  WS_U

__global__ __launch_bounds__(256) void k_init(float* __restrict__ ws) {
    int t = blockIdx.x * 256 + threadIdx.x;
    if (t < 2512) ws[WS_STATS + t] = 0.f;
}

// ---- tiny: W2T[c][kk] = posW2[2][kk][c] (fp32) ----
__global__ __launch_bounds__(256) void k_w2t(const float* __restrict__ posW2,
                                             float* __restrict__ ws) {
    int e = blockIdx.x*256 + threadIdx.x;      // e = c*192 + kk
    int c = e / DD, kk = e - c*DD;
    ws[WS_W2T + e] = posW2[(size_t)(2*DD + kk)*DD + c];
}

// ---- prep: bf16 transposed weight copies (n-major, k-contiguous) ----
__global__ __launch_bounds__(256) void k_prep(
    const float* __restrict__ propW, const float* __restrict__ Wqkv,
    const float* __restrict__ fusW, const float* __restrict__ Wproj,
    const float* __restrict__ posW1, const float* __restrict__ deW2,
    float* __restrict__ ws)
{
    int e = blockIdx.x*256 + threadIdx.x;
    ushort_t* pwt = (ushort_t*)(ws + WS_PROPWT);
    ushort_t* qkt = (ushort_t*)(ws + WS_QKVT);
    ushort_t* fwt = (ushort_t*)(ws + WS_FUSWT);
    ushort_t* pjt = (ushort_t*)(ws + WS_PROJWT);
    ushort_t* w1t = (ushort_t*)(ws + WS_W1T);
    ushort_t* dwt = (ushort_t*)(ws + WS_DEW2T);
    if (e < 36864) {
        int n = e/192, k = e - n*192;
        pwt[e] = f2bf(propW[(size_t)k*192 + n]);
    } else if (e < 147456) {
        int r = e - 36864; int n = r/192, k = r - n*192;
        qkt[r] = f2bf(Wqkv[(size_t)k*576 + n]);
    } else if (e < 184320) {
        int r = e - 147456; int n = r/192, k = r - n*192;
        fwt[r] = f2bf(fusW[(size_t)k*192 + n]);
    } else if (e < 221184) {
        int r = e - 184320; int n = r/192, k = r - n*192;
        pjt[r] = f2bf(Wproj[(size_t)k*192 + n]);
    } else if (e < 258048) {
        int r = e - 221184;
        int i = r / 12288, rem = r - i*12288;
        int n = rem / 64, k = rem - n*64;
        w1t[r] = (k < 48) ? f2bf(posW1[(size_t)(i*48 + k)*DD + n]) : (ushort_t)0;
    } else if (e < 270336) {
        int r = e - 258048;
        int n = r / 64, k = r - n*64;
        dwt[r] = (k < 48) ? f2bf(deW2[(size_t)k*DD + n]) : (ushort_t)0;
    }
}

// ---- cast x -> bf16 ----
__global__ __launch_bounds__(256) void k_castx(const float* __restrict__ x,
                                               float* __restrict__ ws) {
    int e = blockIdx.x*256 + threadIdx.x;
    ((ushort_t*)(ws + WS_XB))[e] = f2bf(x[e]);
}

// ---- K1a: per-(point,neighbor) geometry ----
__global__ __launch_bounds__(256) void k1a_geom(
    const float* __restrict__ p, const int* __restrict__ knn,
    float* __restrict__ ws)
{
    __shared__ float red[32];
    const int t = threadIdx.x;
    const int w = t >> 4, u = t & 15;
    const int n = blockIdx.x*16 + w;
    const int idx = knn[n*NS + u];
    const float X0 = p[idx*3+0], X1 = p[idx*3+1], X2 = p[idx*3+2];
    const float pn0 = p[n*3+0], pn1 = p[n*3+1], pn2 = p[n*3+2];
    ws[WS_KNN + (size_t)n*48 + u*3 + 0] = X0;
    ws[WS_KNN + (size_t)n*48 + u*3 + 1] = X1;
    ws[WS_KNN + (size_t)n*48 + u*3 + 2] = X2;
    const float dx = X0-pn0, dy = X1-pn1, dz = X2-pn2;
    ws[WS_PR + (size_t)(n*NS+u)*3 + 0] = dx;
    ws[WS_PR + (size_t)(n*NS+u)*3 + 1] = dy;
    ws[WS_PR + (size_t)(n*NS+u)*3 + 2] = dz;
    const float dist = sqrtf(dx*dx + dy*dy + dz*dz + 1e-12f);
    float dmx = dist, dsm = dist, S0 = X0, S1 = X1, S2 = X2;
    #pragma unroll
    for (int off = 1; off < 16; off <<= 1) {
        dmx = fmaxf(dmx, __shfl_xor(dmx, off, 16));
        dsm += __shfl_xor(dsm, off, 16);
        S0 += __shfl_xor(S0, off, 16);
        S1 += __shfl_xor(S1, off, 16);
        S2 += __shfl_xor(S2, off, 16);
    }
    if (u == 0) {
        ws[WS_GDIS + n] = dmx;
        float m0 = S0*(1.f/16.f), m1 = S1*(1.f/16.f), m2 = S2*(1.f/16.f);
        float* g = ws + WS_GEO9 + (size_t)n*9;
        g[0] = m0-pn0; g[1] = m1-pn1; g[2] = m2-pn2;
        g[3] = m0; g[4] = m1; g[5] = m2;
        g[6] = pn0; g[7] = pn1; g[8] = pn2;
        red[w] = dsm; red[16+w] = dmx;
    }
    __syncthreads();
    if (t == 0) {
        float ds = 0.f, dm = 0.f;
        #pragma unroll
        for (int i = 0; i < 16; ++i) { ds += red[i]; dm = fmaxf(dm, red[16+i]); }
        atomicAdd(&ws[WS_STATS + 0], ds);
        atomicMax((int*)(ws + WS_STATS + 1), __float_as_int(dm));  // dist>=0
    }
}

// ---- K1b: factored BN stats ----
__global__ __launch_bounds__(256) void k1b_stats(float* __restrict__ ws)
{
    __shared__ float Xs[128][48];
    __shared__ float Ss[128][3];
    __shared__ float a3p[9][16];
    const int t = threadIdx.x;
    const int c0 = blockIdx.x * 128;
    for (int e = t; e < 1536; e += 256) {
        int r = e/12, q = e%12;
        *(float4*)&Xs[r][q*4] = *(const float4*)(ws + WS_KNN + (size_t)(c0+r)*48 + q*4);
    }
    __syncthreads();
    if (t < 128) {
        float s0 = 0.f, s1 = 0.f, s2 = 0.f;
        #pragma unroll
        for (int j = 0; j < 16; ++j) { s0 += Xs[t][3*j]; s1 += Xs[t][3*j+1]; s2 += Xs[t][3*j+2]; }
        Ss[t][0] = s0; Ss[t][1] = s1; Ss[t][2] = s2;
    }
    __syncthreads();
    {
        float acc[9];
        #pragma unroll
        for (int q = 0; q < 9; ++q) acc[q] = 0.f;
        for (int i = 0; i < 128; ++i) {
            int e = t;
            #pragma unroll
            for (int q = 0; q < 9; ++q) {
                int a = e/48, b = e%48;
                acc[q] += Xs[i][a] * Xs[i][b];
                e += 256;
            }
        }
        int e = t;
        #pragma unroll
        for (int q = 0; q < 9; ++q) { atomicAdd(&ws[WS_STATS + 50 + e], acc[q]); e += 256; }
    }
    if (t < 144) {
        int a = t/3, d = t%3;
        float s = 0.f;
        for (int i = 0; i < 128; ++i) s += Xs[i][a] * Ss[i][d];
        atomicAdd(&ws[WS_STATS + 2354 + t], s);
    }
    if (t < 144) {
        int q = t >> 4, part = t & 15;
        int d = q/3, e2 = q%3;
        float s = 0.f;
        for (int i = part*8; i < part*8 + 8; ++i) {
            #pragma unroll
            for (int j = 0; j < 16; ++j) s += Xs[i][3*j+d] * Xs[i][3*j+e2];
        }
        a3p[q][part] = s;
    }
    if (t < 48) {
        float s = 0.f;
        for (int i = 0; i < 128; ++i) s += Xs[i][t];
        atomicAdd(&ws[WS_STATS + 2 + t], s);
    }
    if (t < 3) {
        float s = 0.f;
        for (int i = 0; i < 128; ++i) s += Ss[i][t];
        atomicAdd(&ws[WS_STATS + 2507 + t], s);
    }
    __syncthreads();
    if (t < 9) {
        float s = 0.f;
        #pragma unroll
        for (int i = 0; i < 16; ++i) s += a3p[t][i];
        atomicAdd(&ws[WS_STATS + 2498 + t], s);
    }
}

// ---- K2: vol vector + BN fold (M2 reconstructed from factored stats) ----
__global__ __launch_bounds__(256) void k2_fold(
    const float* __restrict__ posW1, const float* __restrict__ posB1,
    const float* __restrict__ gamma, const float* __restrict__ beta,
    const float* __restrict__ gCW, const float* __restrict__ gCb,
    float* __restrict__ ws)
{
    __shared__ float M2n[48][48];
    __shared__ float pmean[48];
    __shared__ float Wc[48][193];
    const int t = threadIdx.x;
    const int i = blockIdx.x;
    for (int e = t; e < 2304; e += 256) {
        int a = e/48, b = e%48, ad = a%3, bd = b%3;
        float v = 16.f*ws[WS_STATS + 50 + e]
                - ws[WS_STATS + 2354 + a*3 + bd]
                - ws[WS_STATS + 2354 + b*3 + ad]
                + ws[WS_STATS + 2498 + ad*3 + bd];
        M2n[a][b] = v * (1.f/(float)MTOT);
    }
    if (t < 48) pmean[t] = (16.f*ws[WS_STATS + 2 + t] - ws[WS_STATS + 2507 + t%3])
                           * (1.f/(float)MTOT);
    if (t < DD) {
        for (int k = 0; k < 48; ++k) Wc[k][t] = posW1[(size_t)(i*48 + k)*DD + t];
    }
    __syncthreads();
    if (i == 0 && t < DD) {
        float dsum = ws[WS_STATS + 0];
        float dmax = __int_as_float(((const int*)(ws + WS_STATS))[1]);
        float vol = (dsum * (1.f/(float)MTOT)) / (dmax + 1e-8f);
        ws[WS_VOLV + t] = vol * gCW[t] + gCb[t];
    }
    if (t < DD) {
        float mu0 = 0.f;
        #pragma unroll 8
        for (int k = 0; k < 48; ++k) mu0 += pmean[k] * Wc[k][t];
        float e2 = 0.f;
        for (int a2 = 0; a2 < 48; ++a2) {
            float inner = 0.f;
            #pragma unroll 8
            for (int b2 = 0; b2 < 48; ++b2) inner += M2n[a2][b2] * Wc[b2][t];
            e2 += Wc[a2][t] * inner;
        }
        float var = fmaxf(e2 - mu0*mu0, 0.f);
        float as = rsqrtf(var + 1e-5f) * gamma[i*DD + t];
        ws[WS_AB + i*DD + t]       = as;
        ws[WS_AB + 576 + i*DD + t] = beta[i*DD + t] - mu0 * as;   // h'=relu(acc*as+bb)
    }
}

// ---- K_prop MFMA ----
__global__ __launch_bounds__(256) void k_prop_mfma(
    const float* __restrict__ x, const int* __restrict__ knn,
    const float* __restrict__ propW, const float* __restrict__ propB,
    float* __restrict__ ws)
{
    __shared__ ushort_t As[64*40];
    __shared__ ushort_t Bs[192*40];
    __shared__ float prs[64*3];
    __shared__ float W3[3*192];
    __shared__ int idx64[64];
    const int t = threadIdx.x;
    const int mbase = blockIdx.x * 64;
    const ushort_t* xb = (const ushort_t*)(ws + WS_XB);
    const ushort_t* pwt = (const ushort_t*)(ws + WS_PROPWT);
    if (t < 64) idx64[t] = knn[mbase + t];
    for (int e = t; e < 576; e += 256) W3[e] = propW[(size_t)(192 + e/192)*DD + (e % 192)];
    for (int e = t; e < 192; e += 256) prs[e] = ws[WS_PR + (size_t)mbase*3 + e];
    const int wave = t >> 6, lane = t & 63, m = lane & 15, quad = lane >> 4;
    f32x4 acc[12];
    #pragma unroll
    for (int nt = 0; nt < 12; ++nt) acc[nt] = (f32x4){0.f,0.f,0.f,0.f};
    for (int ks = 0; ks < 6; ++ks) {
        const int k0 = ks*32;
        __syncthreads();
        {   int r = t >> 2, seg = t & 3;
            *(uint4*)&As[r*40 + seg*8] = *(const uint4*)(xb + (size_t)idx64[r]*192 + k0 + seg*8);
        }
        for (int e = t; e < 768; e += 256) {
            int n = e >> 2, seg = e & 3;
            *(uint4*)&Bs[n*40 + seg*8] = *(const uint4*)(pwt + (size_t)n*192 + k0 + seg*8);
        }
        __syncthreads();
        short8 a = *(const short8*)&As[(wave*16 + m)*40 + quad*8];
        #pragma unroll
        for (int nt = 0; nt < 12; ++nt) {
            short8 b = *(const short8*)&Bs[(nt*16 + m)*40 + quad*8];
            acc[nt] = __builtin_amdgcn_mfma_f32_16x16x32_bf16(a, b, acc[nt], 0, 0, 0);
        }
    }
    const int n = blockIdx.x*4 + wave;
    #pragma unroll
    for (int nt = 0; nt < 12; ++nt) {
        int col = nt*16 + m;
        float bv = propB[col];
        float w0 = W3[col], w1 = W3[192 + col], w2 = W3[384 + col];
        float s = 0.f;
        #pragma unroll
        for (int reg = 0; reg < 4; ++reg) {
            int j = wave*16 + quad*4 + reg;
            float v = acc[nt][reg] + prs[j*3+0]*w0 + prs[j*3+1]*w1 + prs[j*3+2]*w2 + bv;
            s += fmaxf(v, 0.f);
        }
        s += __shfl_xor(s, 16);
        s += __shfl_xor(s, 32);
        if (quad == 0)
            ws[WS_X1 + (size_t)n*DD + col] = x[(size_t)n*DD + col] + s * (1.f/16.f);
    }
}

// ---- generic bf16 MFMA GEMM ----
__global__ __launch_bounds__(256) void gemm_mfma(
    const ushort_t* __restrict__ A, const ushort_t* __restrict__ Bt,
    const float* __restrict__ bias, float* __restrict__ Cf,
    ushort_t* __restrict__ Cb, int N)
{
    __shared__ ushort_t As[64*40];
    __shared__ ushort_t Bs[64*40];
    const int t = threadIdx.x;
    const int wave = t >> 6, lane = t & 63, m = lane & 15, quad = lane >> 4;
    const int rowBase = blockIdx.x * 64, colBase = blockIdx.y * 64;
    f32x4 acc[4];
    #pragma unroll
    for (int nt = 0; nt < 4; ++nt) acc[nt] = (f32x4){0.f,0.f,0.f,0.f};
    for (int ks = 0; ks < 6; ++ks) {
        __syncthreads();
        {   int r = t >> 2, seg = t & 3;
            *(uint4*)&As[r*40 + seg*8] = *(const uint4*)(A + (size_t)(rowBase + r)*192 + ks*32 + seg*8);
            *(uint4*)&Bs[r*40 + seg*8] = *(const uint4*)(Bt + (size_t)(colBase + r)*192 + ks*32 + seg*8);
        }
        __syncthreads();
        short8 a = *(const short8*)&As[(wave*16 + m)*40 + quad*8];
        #pragma unroll
        for (int nt = 0; nt < 4; ++nt) {
            short8 b = *(const short8*)&Bs[(nt*16 + m)*40 + quad*8];
            acc[nt] = __builtin_amdgcn_mfma_f32_16x16x32_bf16(a, b, acc[nt], 0, 0, 0);
        }
    }
    #pragma unroll
    for (int nt = 0; nt < 4; ++nt) {
        int col = colBase + nt*16 + m;
        float bv = bias ? bias[col] : 0.f;
        #pragma unroll
        for (int reg = 0; reg < 4; ++reg) {
            int row = rowBase + wave*16 + quad*4 + reg;
            float v = acc[nt][reg] + bv;
            if (Cf) Cf[(size_t)row*N + col] = v;
            else    Cb[(size_t)row*N + col] = f2bf(v);
        }
    }
}

// ---- K3a v2: keypoint attention via MFMA (8 points/block) + U assembly ----
__global__ __launch_bounds__(256) void k3a(
    const float* __restrict__ p, const float* __restrict__ kn,
    const float* __restrict__ deW1, const float* __restrict__ deB1,
    const float* __restrict__ deB2, const float* __restrict__ kpW,
    const float* __restrict__ gAW, const float* __restrict__ gAb,
    const float* __restrict__ gBW, const float* __restrict__ gBb,
    float* __restrict__ ws)
{
    __shared__ ushort_t fb[128*72];     // f rows bf16, K pad 64, stride 72
    __shared__ float kds[8][16];
    __shared__ float w1s[48], b1s[48];
    __shared__ float dfeat[8][192];
    ushort_t* ub = (ushort_t*)(ws + WS_UB);
    const int t = threadIdx.x;
    const int nb = blockIdx.x * 8;
    if (t < 48) { w1s[t] = deW1[t]; b1s[t] = deB1[t]; }
    if (t < 128) {
        int w = t >> 4, kp = t & 15;
        float dx = p[(nb+w)*3+0]-kn[kp*3+0];
        float dy = p[(nb+w)*3+1]-kn[kp*3+1];
        float dz = p[(nb+w)*3+2]-kn[kp*3+2];
        kds[w][kp] = sqrtf(dx*dx + dy*dy + dz*dz + 1e-12f);
    }
    __syncthreads();
    for (int e = t; e < 128*64; e += 256) {   // f = relu(kd*w1+b1), bf16 A tile
        int j = e >> 6, k = e & 63;
        float v = (k < 48) ? fmaxf(kds[j>>4][j&15]*w1s[k] + b1s[k], 0.f) : 0.f;
        fb[j*72 + k] = f2bf(v);
    }
    __syncthreads();
    const int wave = t >> 6, lane = t & 63, m = lane & 15, quad = lane >> 4;
    const ushort_t* dwt = (const ushort_t*)(ws + WS_DEW2T);
    short8 afr[2][2];
    #pragma unroll
    for (int mt = 0; mt < 2; ++mt)
        #pragma unroll
        for (int ks = 0; ks < 2; ++ks)
            afr[mt][ks] = *(const short8*)&fb[((wave*2 + mt)*16 + m)*72 + ks*32 + quad*8];
    float df[2][12][4];
    float sc[2][4];
    #pragma unroll
    for (int mt = 0; mt < 2; ++mt)
        #pragma unroll
        for (int reg = 0; reg < 4; ++reg) sc[mt][reg] = 0.f;
    for (int nt = 0; nt < 12; ++nt) {
        f32x4 acc0 = (f32x4){0.f,0.f,0.f,0.f};
        f32x4 acc1 = (f32x4){0.f,0.f,0.f,0.f};
        #pragma unroll
        for (int ks = 0; ks < 2; ++ks) {
            short8 b = *(const short8*)(dwt + ((size_t)(nt*16 + m)*64 + ks*32 + quad*8));
            acc0 = __builtin_amdgcn_mfma_f32_16x16x32_bf16(afr[0][ks], b, acc0, 0, 0, 0);
            acc1 = __builtin_amdgcn_mfma_f32_16x16x32_bf16(afr[1][ks], b, acc1, 0, 0, 0);
        }
        int col = nt*16 + m;
        float b2 = deB2[col], kw = kpW[col];
        #pragma unroll
        for (int reg = 0; reg < 4; ++reg) {
            float d0 = acc0[reg] + b2, d1 = acc1[reg] + b2;
            df[0][nt][reg] = d0; df[1][nt][reg] = d1;
            sc[0][reg] += d0*kw; sc[1][reg] += d1*kw;
        }
    }
    #pragma unroll
    for (int mt = 0; mt < 2; ++mt)     // reduce score over m lanes (width 16)
        #pragma unroll
        for (int reg = 0; reg < 4; ++reg) {
            float v = sc[mt][reg];
            v += __shfl_xor(v, 1, 16); v += __shfl_xor(v, 2, 16);
            v += __shfl_xor(v, 4, 16); v += __shfl_xor(v, 8, 16);
            sc[mt][reg] = v;
        }
    float wgt[2][4];
    #pragma unroll
    for (int mt = 0; mt < 2; ++mt) {   // softmax over kp = quad*4+reg (kpB const: dropped)
        float mx = fmaxf(fmaxf(sc[mt][0], sc[mt][1]), fmaxf(sc[mt][2], sc[mt][3]));
        mx = fmaxf(mx, __shfl_xor(mx, 16));
        mx = fmaxf(mx, __shfl_xor(mx, 32));
        float sm = 0.f;
        #pragma unroll
        for (int reg = 0; reg < 4; ++reg) { wgt[mt][reg] = expf(sc[mt][reg] - mx); sm += wgt[mt][reg]; }
        sm += __shfl_xor(sm, 16);
        sm += __shfl_xor(sm, 32);
        float inv = 1.f / sm;
        #pragma unroll
        for (int reg = 0; reg < 4; ++reg) wgt[mt][reg] *= inv;
    }
    for (int nt = 0; nt < 12; ++nt) {  // dfeat = attn-weighted kp-reduction
        int col = nt*16 + m;
        #pragma unroll
        for (int mt = 0; mt < 2; ++mt) {
            float s = 0.f;
            #pragma unroll
            for (int reg = 0; reg < 4; ++reg) s += wgt[mt][reg] * df[mt][nt][reg];
            s += __shfl_xor(s, 16);
            s += __shfl_xor(s, 32);
            if (quad == 0) dfeat[wave*2 + mt][col] = s;
        }
    }
    __syncthreads();
    if (t < DD) {                      // U assembly -> bf16 UB
        for (int w = 0; w < 8; ++w) {
            int n = nb + w;
            float uval = ws[WS_X1 + (size_t)n*DD + t] + gAb[t] + gBb[t]
                       + ws[WS_VOLV + t] + dfeat[w][t];
            uval += ws[WS_GDIS + n] * gBW[t];
            #pragma unroll
            for (int kk = 0; kk < 9; ++kk) uval += ws[WS_GEO9 + (size_t)n*9 + kk] * gAW[kk*DD + t];
            ub[(size_t)n*DD + t] = f2bf(uval);
        }
    }
}

// ---- K_attn_fused: 4 windows/block (37.9KB LDS -> 4 blocks/CU) ----
__global__ __launch_bounds__(256, 4) void k_attn_fused(
    const int* __restrict__ knn,
    const float* __restrict__ posW2, const float* __restrict__ posB2,
    float* __restrict__ ws)
{
    __shared__ ushort_t posb[64*72];    // bf16 pos rows, K pad 64, stride 72
    __shared__ float rqs[4*6*192];      // rq per i; later wsum
    __shared__ float qk[4*192];         // q0 (i=0) / k0 (i=1), reloaded per i
    __shared__ float scb[4*192];        // sc[w][i(2)][h(6)][j(16)]
    __shared__ float dqk[4*96];         // dqk[w][h][j]
    __shared__ float attns[4*96];
    __shared__ float Xl[4][48];
    __shared__ int idxs[64];
    const int t = threadIdx.x;
    const int nb = blockIdx.x * 4;
    ushort_t* ctrb = (ushort_t*)(ws + WS_CTRB);
    const ushort_t* qkvb = (const ushort_t*)(ws + WS_QKV);
    if (t < 64) idxs[t] = knn[(nb + (t >> 4))*NS + (t & 15)];
    if (t < 192) {
        int w = t/48, k = t%48;
        Xl[w][k] = ws[WS_KNN + (size_t)(nb+w)*48 + k];
    }
    __syncthreads();
    for (int e = t; e < 64*64; e += 256) {   // build bf16 pos tile
        int j = e >> 6, k = e & 63;
        int w = j >> 4, jl = j & 15;
        float v = (k < 48) ? (Xl[w][k] - Xl[w][jl*3 + (k % 3)]) : 0.f;
        posb[j*72 + k] = f2bf(v);
    }
    const int wave = t >> 6, lane = t & 63, m = lane & 15, quad = lane >> 4;
    const ushort_t* w1t = (const ushort_t*)(ws + WS_W1T);
    // ---- i = 0,1: rq + MFMA H + fused contraction -> scb ----
    for (int i = 0; i < 2; ++i) {
        __syncthreads();   // posb built (i=0) / prior rqs,qk readers done (i=1)
        for (int e = t; e < 4*192; e += 256) {
            int w = e/192, c = e%192;
            qk[e] = bf2f(qkvb[(size_t)idxs[w*16]*576 + i*192 + c]);
        }
        __syncthreads();
        if (t < 192) {     // rq: W2 row t (global) x qk broadcast
            const float* Wrow = posW2 + (size_t)i*DD*DD + (size_t)t*DD;
            for (int h = 0; h < 6; ++h) {
                float4 wr[8];
                #pragma unroll
                for (int q = 0; q < 8; ++q) wr[q] = *(const float4*)(Wrow + h*32 + q*4);
                float a[4];
                #pragma unroll
                for (int w = 0; w < 4; ++w) a[w] = 0.f;
                #pragma unroll
                for (int q = 0; q < 8; ++q) {
                    #pragma unroll
                    for (int d = 0; d < 4; ++d) {
                        float wv = (&wr[q].x)[d];
                        int c = h*32 + q*4 + d;
                        #pragma unroll
                        for (int w = 0; w < 4; ++w) a[w] += wv * qk[w*192 + c];
                    }
                }
                #pragma unroll
                for (int w = 0; w < 4; ++w) rqs[(w*6 + h)*192 + t] = a[w];
            }
        }
        __syncthreads();
        short8 afr[2];
        #pragma unroll
        for (int ks = 0; ks < 2; ++ks)
            afr[ks] = *(const short8*)&posb[(wave*16 + m)*72 + ks*32 + quad*8];
        float s[24];       // [reg(4)][h(6)] for this wave's window
        #pragma unroll
        for (int e = 0; e < 24; ++e) s[e] = 0.f;
        for (int nt = 0; nt < 12; ++nt) {
            f32x4 acc0 = (f32x4){0.f,0.f,0.f,0.f};
            #pragma unroll
            for (int ks = 0; ks < 2; ++ks) {
                short8 b = *(const short8*)(w1t + ((size_t)(i*192 + nt*16 + m)*64 + ks*32 + quad*8));
                acc0 = __builtin_amdgcn_mfma_f32_16x16x32_bf16(afr[ks], b, acc0, 0, 0, 0);
            }
            int kk = nt*16 + m;
            float as = ws[WS_AB + i*DD + kk];
            float bb = ws[WS_AB + 576 + i*DD + kk];
            float h0[4];
            #pragma unroll
            for (int reg = 0; reg < 4; ++reg)
                h0[reg] = fmaxf(acc0[reg]*as + bb, 0.f);
            #pragma unroll
            for (int h = 0; h < 6; ++h) {
                float r0 = rqs[(wave*6 + h)*192 + kk];
                #pragma unroll
                for (int reg = 0; reg < 4; ++reg)
                    s[reg*6 + h] += h0[reg]*r0;
            }
        }
        #pragma unroll
        for (int e = 0; e < 24; ++e) {
            float v = s[e];
            v += __shfl_xor(v, 1, 16); v += __shfl_xor(v, 2, 16);
            v += __shfl_xor(v, 4, 16); v += __shfl_xor(v, 8, 16);
            s[e] = v;
        }
        if (m == 0) {
            #pragma unroll
            for (int reg = 0; reg < 4; ++reg) {
                int j = quad*4 + reg;
                #pragma unroll
                for (int h = 0; h < 6; ++h)
                    scb[wave*192 + i*96 + h*16 + j] = s[reg*6 + h];
            }
        }
    }
    // ---- dqk dots: thread -> (w, j, half); bf16 rows ----
    if (t < 128) {
        const int w = t >> 5, r = t & 31, j = r >> 1, half = r & 1;
        const ushort_t* krow = qkvb + (size_t)idxs[w*16 + j]*576 + 192 + half*96;
        const ushort_t* qrow = qkvb + (size_t)idxs[w*16]*576 + half*96;
        float hd[3] = {0.f, 0.f, 0.f};
        #pragma unroll
        for (int q = 0; q < 12; ++q) {
            uint4 kv = *(const uint4*)(krow + q*8);
            uint4 qv = *(const uint4*)(qrow + q*8);
            float sv = 0.f;
            #pragma unroll
            for (int d = 0; d < 4; ++d) {
                unsigned int ku = (&kv.x)[d], qu = (&qv.x)[d];
                sv += __uint_as_float(ku << 16) * __uint_as_float(qu << 16);
                sv += __uint_as_float(ku & 0xffff0000u) * __uint_as_float(qu & 0xffff0000u);
            }
            hd[q >> 2] += sv;
        }
        dqk[w*96 + (half*3+0)*16 + j] = hd[0];
        dqk[w*96 + (half*3+1)*16 + j] = hd[1];
        dqk[w*96 + (half*3+2)*16 + j] = hd[2];
    }
    __syncthreads();   // dqk+scb ready; also all rqs reads (i=1) done
    // ---- softmax over j per (w,h): 4*6*16 = 384 elements ----
    {
        const float scale = 0.17677669529663687f;  // 32^-0.5
        #pragma unroll
        for (int c = 0; c < 2; ++c) {
            int e = c*256 + t;
            if (e < 384) {
                int row = e >> 4, j = e & 15, w = row / 6, h = row % 6;
                float z = (dqk[e] + scb[w*192 + h*16 + j] + scb[w*192 + 96 + h*16 + j]) * scale;
                float mx = z;
                #pragma unroll
                for (int off = 1; off < 16; off <<= 1) mx = fmaxf(mx, __shfl_xor(mx, off, 16));
                float ex = expf(z - mx);
                float sm = ex;
                #pragma unroll
                for (int off = 1; off < 16; off <<= 1) sm += __shfl_xor(sm, off, 16);
                attns[w*96 + h*16 + j] = ex / sm;
            }
        }
    }
    __syncthreads();   // attns ready
    // ---- ctr1 = attn @ v (bf16 V rows) ----
    float ctr1[4];
    if (t < DD) {
        const int h = t >> 5;
        #pragma unroll
        for (int w = 0; w < 4; ++w) {
            float sv = 0.f;
            #pragma unroll
            for (int j = 0; j < NS; ++j)
                sv += attns[w*96 + h*16 + j] * bf2f(qkvb[(size_t)idxs[w*16 + j]*576 + 384 + t]);
            ctr1[w] = sv;
        }
    }
    // ---- H2 MFMA + attn-weighted reduce -> wsum (rqs region) ----
    {
        float* wsum = rqs;
        short8 afr[2];
        #pragma unroll
        for (int ks = 0; ks < 2; ++ks)
            afr[ks] = *(const short8*)&posb[(wave*16 + m)*72 + ks*32 + quad*8];
        for (int nt = 0; nt < 12; ++nt) {
            f32x4 acc0 = (f32x4){0.f,0.f,0.f,0.f};
            #pragma unroll
            for (int ks = 0; ks < 2; ++ks) {
                short8 b = *(const short8*)(w1t + ((size_t)(2*192 + nt*16 + m)*64 + ks*32 + quad*8));
                acc0 = __builtin_amdgcn_mfma_f32_16x16x32_bf16(afr[ks], b, acc0, 0, 0, 0);
            }
            int kk = nt*16 + m;
            float as = ws[WS_AB + 2*DD + kk];
            float bb = ws[WS_AB + 576 + 2*DD + kk];
            float h0[4];
            #pragma unroll
            for (int reg = 0; reg < 4; ++reg)
                h0[reg] = fmaxf(acc0[reg]*as + bb, 0.f);
            #pragma unroll
            for (int h = 0; h < 6; ++h) {
                float p0 = 0.f;
                #pragma unroll
                for (int reg = 0; reg < 4; ++reg) {
                    int j = quad*4 + reg;
                    p0 += attns[wave*96 + h*16 + j] * h0[reg];
                }
                p0 += __shfl_xor(p0, 16); p0 += __shfl_xor(p0, 32);
                if (quad == 0) wsum[(wave*6 + h)*192 + kk] = p0;
            }
        }
    }
    __syncthreads();   // wsum ready
    // ---- pv = wsum @ W2_2 via W2T rows; CTR = ctr1 + pv + b2 ----
    if (t < DD) {
        const float* wsum = rqs;
        const int h = t >> 5;
        float pvacc[4];
        #pragma unroll
        for (int w = 0; w < 4; ++w) pvacc[w] = 0.f;
        const float* wrow = ws + WS_W2T + (size_t)t*DD;
        for (int k4 = 0; k4 < 48; ++k4) {
            float4 wv = *(const float4*)(wrow + k4*4);
            #pragma unroll
            for (int w = 0; w < 4; ++w) {
                const float* av = &wsum[(w*6 + h)*192 + k4*4];
                pvacc[w] += av[0]*wv.x + av[1]*wv.y + av[2]*wv.z + av[3]*wv.w;
            }
        }
        float b2 = posB2[2*DD + t];
        #pragma unroll
        for (int w = 0; w < 4; ++w)
            ctrb[(size_t)(nb+w)*DD + t] = f2bf(ctr1[w] + pvacc[w] + b2);
    }
}

extern "C" void kernel_launch(void* const* d_in, const int* in_sizes, int n_in,
                              void* d_out, int out_size, void* d_ws, size_t ws_size,
                              hipStream_t stream)
{
    const float* p     = (const float*)d_in[0];
    const float* x     = (const float*)d_in[1];
    const int*   knn   = (const int*)  d_in[2];
    const float* Wqkv  = (const float*)d_in[3];
    const float* Wproj = (const float*)d_in[4];
    const float* bproj = (const float*)d_in[5];
    const float* propW = (const float*)d_in[6];
    const float* propB = (const float*)d_in[7];
    const float* gAW   = (const float*)d_in[8];
    const float* gAb   = (const float*)d_in[9];
    const float* gBW   = (const float*)d_in[10];
    const float* gBb   = (const float*)d_in[11];
    const float* gCW   = (const float*)d_in[12];
    const float* gCb   = (const float*)d_in[13];
    const float* posW1 = (const float*)d_in[14];
    const float* posB1 = (const float*)d_in[15];
    const float* gamma = (const float*)d_in[16];
    const float* beta  = (const float*)d_in[17];
    const float* posW2 = (const float*)d_in[18];
    const float* posB2 = (const float*)d_in[19];
    const float* kn    = (const float*)d_in[20];
    const float* deW1  = (const float*)d_in[21];
    const float* deB1  = (const float*)d_in[22];
    const float* deW2  = (const float*)d_in[23];
    const float* deB2  = (const float*)d_in[24];
    const float* kpW   = (const float*)d_in[25];
    const float* kpB   = (const float*)d_in[26];
    const float* fusW  = (const float*)d_in[27];
    const float* fusB  = (const float*)d_in[28];
    float* ws   = (float*)d_ws;
    float* outp = (float*)d_out;
    (void)kpB;  // constant shift inside softmax: invariant, dropped

    hipLaunchKernelGGL(k_init, dim3(10), dim3(256), 0, stream, ws);
    hipLaunchKernelGGL(k_w2t, dim3(144), dim3(256), 0, stream, posW2, ws);
    hipLaunchKernelGGL(k_prep, dim3(1056), dim3(256), 0, stream,
                       propW, Wqkv, fusW, Wproj, posW1, deW2, ws);
    hipLaunchKernelGGL(k_castx, dim3(NP*DD/256), dim3(256), 0, stream, x, ws);
    hipLaunchKernelGGL(k1a_geom, dim3(NP/16), dim3(256), 0, stream, p, knn, ws);
    hipLaunchKernelGGL(k1b_stats, dim3(NP/128), dim3(256), 0, stream, ws);
    hipLaunchKernelGGL(k2_fold, dim3(3), dim3(256), 0, stream,
                       posW1, posB1, gamma, beta, gCW, gCb, ws);
    hipLaunchKernelGGL(k_prop_mfma, dim3(MTOT/64), dim3(256), 0, stream,
                       x, knn, propW, propB, ws);
    hipLaunchKernelGGL(k3a, dim3(NP/8), dim3(256), 0, stream,
                       p, kn, deW1, deB1, deB2, kpW, gAW, gAb, gBW, gBb, ws);
    // X2B = bf16(UB @ fusW + fusB)
    hipLaunchKernelGGL(gemm_mfma, dim3(NP/64, 3), dim3(256), 0, stream,
                       (const ushort_t*)(ws + WS_UB), (const ushort_t*)(ws + WS_FUSWT),
                       fusB, (float*)nullptr, (ushort_t*)(ws + WS_X2B), DD);
    // QKV = bf16(X2B @ Wqkv)
    hipLaunchKernelGGL(gemm_mfma, dim3(NP/64, 9), dim3(256), 0, stream,
                       (const ushort_t*)(ws + WS_X2B), (const ushort_t*)(ws + WS_QKVT),
                       (const float*)nullptr, (float*)nullptr,
                       (ushort_t*)(ws + WS_QKV), 576);
    hipLaunchKernelGGL(k_attn_fused, dim3(NP/4), dim3(256), 0, stream,
                       knn, posW2, posB2, ws);
    // OUT = CTRB @ Wproj + bproj (fp32 out)
    hipLaunchKernelGGL(gemm_mfma, dim3(NP/64, 3), dim3(256), 0, stream,
                       (const ushort_t*)(ws + WS_CTRB), (const ushort_t*)(ws + WS_PROJWT),
                       bproj, outp, (ushort_t*)nullptr, DD);
}

// Round 3
// 611.147 us; speedup vs baseline: 1.2123x; 1.2123x over previous
//
#include <hip/hip_runtime.h>
#include <math.h>

#define NP 16384
#define DD 192
#define NS 16
#define KSPN 16
#define MTOT (NP*NS)

typedef unsigned short ushort_t;
typedef __attribute__((ext_vector_type(8))) short short8;
typedef __attribute__((ext_vector_type(4))) float f32x4;

__device__ __forceinline__ ushort_t f2bf(float f) {
    union { float f; unsigned int u; } v; v.f = f;
    return (ushort_t)((v.u + 0x7FFFu + ((v.u >> 16) & 1u)) >> 16);
}
__device__ __forceinline__ float bf2f(ushort_t u) {
    return __uint_as_float(((unsigned int)u) << 16);
}

// ws float offsets
#define WS_KNN   0                         // NP*48   knn_xyz
#define WS_PR    (WS_KNN + NP*48)          // MTOT*3  p_r per window row
#define WS_GEO9  (WS_PR + MTOT*3)          // NP*9
#define WS_GDIS  (WS_GEO9 + NP*9)          // NP
// STATS: [0]=dsum [1]=dmax(bits) [2..50)=sumX [50..2354)=A1 [2354..2498)=A2
//        [2498..2507)=A3 [2507..2510)=sumS
#define WS_STATS (WS_GDIS + NP)
#define WS_VOLV  (WS_STATS + 2512)         // 192
#define WS_AB    (WS_VOLV + DD)            // a[3][192] | bb[3][192] = 1152
#define WS_X1    (WS_AB + 1152)            // NP*192 post-propagate (consumed by k3a)
#define WS_U     (WS_X1 + NP*DD)           // NP*192: CTRB (bf16) after fused attn
#define WS_X2    (WS_U + NP*DD)            // NP*192: X2B (bf16, written by fus gemm)
#define WS_QKV   (WS_X2 + NP*DD)           // NP*576 bf16 (uses half the region)
#define WS_SC    (WS_QKV + NP*576)         // region: XB overlay (bf16 x)
#define WS_ATTN  (WS_SC + NP*DD)           // region: UB overlay (bf16 U)
#define WS_W2T   (WS_ATTN + NP*96)         // 192*192 transposed posW2[2] fp32
#define WS_PROPWT (WS_W2T + 36864)         // 18432 floats (bf16 transposed propW[:192])
#define WS_QKVT  (WS_PROPWT + 18432)       // 55296
#define WS_FUSWT (WS_QKVT + 55296)         // 18432
#define WS_PROJWT (WS_FUSWT + 18432)       // 18432
#define WS_W1T   (WS_PROJWT + 18432)       // 3*192*64 bf16 = 18432 floats (K pad 64)
#define WS_DEW2T (WS_W1T + 18432)          // 192*64 bf16 = 6144 floats (deW2 transposed, K pad 64)
// overlays (bf16 arrays in dead-interval regions):
#define WS_XB    WS_SC
#define WS_UB    WS_ATTN
#define WS_X2B   WS_X2
#define WS_CTRB  WS_U

__global__ __launch_bounds__(256) void k_init(float* __restrict__ ws) {
    int t = blockIdx.x * 256 + threadIdx.x;
    if (t < 2512) ws[WS_STATS + t] = 0.f;
}

// ---- tiny: W2T[c][kk] = posW2[2][kk][c] (fp32) ----
__global__ __launch_bounds__(256) void k_w2t(const float* __restrict__ posW2,
                                             float* __restrict__ ws) {
    int e = blockIdx.x*256 + threadIdx.x;      // e = c*192 + kk
    int c = e / DD, kk = e - c*DD;
    ws[WS_W2T + e] = posW2[(size_t)(2*DD + kk)*DD + c];
}

// ---- prep: bf16 transposed weight copies (n-major, k-contiguous) ----
__global__ __launch_bounds__(256) void k_prep(
    const float* __restrict__ propW, const float* __restrict__ Wqkv,
    const float* __restrict__ fusW, const float* __restrict__ Wproj,
    const float* __restrict__ posW1, const float* __restrict__ deW2,
    float* __restrict__ ws)
{
    int e = blockIdx.x*256 + threadIdx.x;
    ushort_t* pwt = (ushort_t*)(ws + WS_PROPWT);
    ushort_t* qkt = (ushort_t*)(ws + WS_QKVT);
    ushort_t* fwt = (ushort_t*)(ws + WS_FUSWT);
    ushort_t* pjt = (ushort_t*)(ws + WS_PROJWT);
    ushort_t* w1t = (ushort_t*)(ws + WS_W1T);
    ushort_t* dwt = (ushort_t*)(ws + WS_DEW2T);
    if (e < 36864) {
        int n = e/192, k = e - n*192;
        pwt[e] = f2bf(propW[(size_t)k*192 + n]);
    } else if (e < 147456) {
        int r = e - 36864; int n = r/192, k = r - n*192;
        qkt[r] = f2bf(Wqkv[(size_t)k*576 + n]);
    } else if (e < 184320) {
        int r = e - 147456; int n = r/192, k = r - n*192;
        fwt[r] = f2bf(fusW[(size_t)k*192 + n]);
    } else if (e < 221184) {
        int r = e - 184320; int n = r/192, k = r - n*192;
        pjt[r] = f2bf(Wproj[(size_t)k*192 + n]);
    } else if (e < 258048) {
        int r = e - 221184;
        int i = r / 12288, rem = r - i*12288;
        int n = rem / 64, k = rem - n*64;
        w1t[r] = (k < 48) ? f2bf(posW1[(size_t)(i*48 + k)*DD + n]) : (ushort_t)0;
    } else if (e < 270336) {
        int r = e - 258048;
        int n = r / 64, k = r - n*64;
        dwt[r] = (k < 48) ? f2bf(deW2[(size_t)k*DD + n]) : (ushort_t)0;
    }
}

// ---- cast x -> bf16 ----
__global__ __launch_bounds__(256) void k_castx(const float* __restrict__ x,
                                               float* __restrict__ ws) {
    int e = blockIdx.x*256 + threadIdx.x;
    ((ushort_t*)(ws + WS_XB))[e] = f2bf(x[e]);
}

// ---- K1a: per-(point,neighbor) geometry ----
__global__ __launch_bounds__(256) void k1a_geom(
    const float* __restrict__ p, const int* __restrict__ knn,
    float* __restrict__ ws)
{
    __shared__ float red[32];
    const int t = threadIdx.x;
    const int w = t >> 4, u = t & 15;
    const int n = blockIdx.x*16 + w;
    const int idx = knn[n*NS + u];
    const float X0 = p[idx*3+0], X1 = p[idx*3+1], X2 = p[idx*3+2];
    const float pn0 = p[n*3+0], pn1 = p[n*3+1], pn2 = p[n*3+2];
    ws[WS_KNN + (size_t)n*48 + u*3 + 0] = X0;
    ws[WS_KNN + (size_t)n*48 + u*3 + 1] = X1;
    ws[WS_KNN + (size_t)n*48 + u*3 + 2] = X2;
    const float dx = X0-pn0, dy = X1-pn1, dz = X2-pn2;
    ws[WS_PR + (size_t)(n*NS+u)*3 + 0] = dx;
    ws[WS_PR + (size_t)(n*NS+u)*3 + 1] = dy;
    ws[WS_PR + (size_t)(n*NS+u)*3 + 2] = dz;
    const float dist = sqrtf(dx*dx + dy*dy + dz*dz + 1e-12f);
    float dmx = dist, dsm = dist, S0 = X0, S1 = X1, S2 = X2;
    #pragma unroll
    for (int off = 1; off < 16; off <<= 1) {
        dmx = fmaxf(dmx, __shfl_xor(dmx, off, 16));
        dsm += __shfl_xor(dsm, off, 16);
        S0 += __shfl_xor(S0, off, 16);
        S1 += __shfl_xor(S1, off, 16);
        S2 += __shfl_xor(S2, off, 16);
    }
    if (u == 0) {
        ws[WS_GDIS + n] = dmx;
        float m0 = S0*(1.f/16.f), m1 = S1*(1.f/16.f), m2 = S2*(1.f/16.f);
        float* g = ws + WS_GEO9 + (size_t)n*9;
        g[0] = m0-pn0; g[1] = m1-pn1; g[2] = m2-pn2;
        g[3] = m0; g[4] = m1; g[5] = m2;
        g[6] = pn0; g[7] = pn1; g[8] = pn2;
        red[w] = dsm; red[16+w] = dmx;
    }
    __syncthreads();
    if (t == 0) {
        float ds = 0.f, dm = 0.f;
        #pragma unroll
        for (int i = 0; i < 16; ++i) { ds += red[i]; dm = fmaxf(dm, red[16+i]); }
        atomicAdd(&ws[WS_STATS + 0], ds);
        atomicMax((int*)(ws + WS_STATS + 1), __float_as_int(dm));  // dist>=0
    }
}

// ---- K1b: factored BN stats ----
__global__ __launch_bounds__(256) void k1b_stats(float* __restrict__ ws)
{
    __shared__ float Xs[128][48];
    __shared__ float Ss[128][3];
    __shared__ float a3p[9][16];
    const int t = threadIdx.x;
    const int c0 = blockIdx.x * 128;
    for (int e = t; e < 1536; e += 256) {
        int r = e/12, q = e%12;
        *(float4*)&Xs[r][q*4] = *(const float4*)(ws + WS_KNN + (size_t)(c0+r)*48 + q*4);
    }
    __syncthreads();
    if (t < 128) {
        float s0 = 0.f, s1 = 0.f, s2 = 0.f;
        #pragma unroll
        for (int j = 0; j < 16; ++j) { s0 += Xs[t][3*j]; s1 += Xs[t][3*j+1]; s2 += Xs[t][3*j+2]; }
        Ss[t][0] = s0; Ss[t][1] = s1; Ss[t][2] = s2;
    }
    __syncthreads();
    {
        float acc[9];
        #pragma unroll
        for (int q = 0; q < 9; ++q) acc[q] = 0.f;
        for (int i = 0; i < 128; ++i) {
            int e = t;
            #pragma unroll
            for (int q = 0; q < 9; ++q) {
                int a = e/48, b = e%48;
                acc[q] += Xs[i][a] * Xs[i][b];
                e += 256;
            }
        }
        int e = t;
        #pragma unroll
        for (int q = 0; q < 9; ++q) { atomicAdd(&ws[WS_STATS + 50 + e], acc[q]); e += 256; }
    }
    if (t < 144) {
        int a = t/3, d = t%3;
        float s = 0.f;
        for (int i = 0; i < 128; ++i) s += Xs[i][a] * Ss[i][d];
        atomicAdd(&ws[WS_STATS + 2354 + t], s);
    }
    if (t < 144) {
        int q = t >> 4, part = t & 15;
        int d = q/3, e2 = q%3;
        float s = 0.f;
        for (int i = part*8; i < part*8 + 8; ++i) {
            #pragma unroll
            for (int j = 0; j < 16; ++j) s += Xs[i][3*j+d] * Xs[i][3*j+e2];
        }
        a3p[q][part] = s;
    }
    if (t < 48) {
        float s = 0.f;
        for (int i = 0; i < 128; ++i) s += Xs[i][t];
        atomicAdd(&ws[WS_STATS + 2 + t], s);
    }
    if (t < 3) {
        float s = 0.f;
        for (int i = 0; i < 128; ++i) s += Ss[i][t];
        atomicAdd(&ws[WS_STATS + 2507 + t], s);
    }
    __syncthreads();
    if (t < 9) {
        float s = 0.f;
        #pragma unroll
        for (int i = 0; i < 16; ++i) s += a3p[t][i];
        atomicAdd(&ws[WS_STATS + 2498 + t], s);
    }
}

// ---- K2: vol vector + BN fold (M2 reconstructed from factored stats) ----
__global__ __launch_bounds__(256) void k2_fold(
    const float* __restrict__ posW1, const float* __restrict__ posB1,
    const float* __restrict__ gamma, const float* __restrict__ beta,
    const float* __restrict__ gCW, const float* __restrict__ gCb,
    float* __restrict__ ws)
{
    __shared__ float M2n[48][48];
    __shared__ float pmean[48];
    __shared__ float Wc[48][193];
    const int t = threadIdx.x;
    const int i = blockIdx.x;
    for (int e = t; e < 2304; e += 256) {
        int a = e/48, b = e%48, ad = a%3, bd = b%3;
        float v = 16.f*ws[WS_STATS + 50 + e]
                - ws[WS_STATS + 2354 + a*3 + bd]
                - ws[WS_STATS + 2354 + b*3 + ad]
                + ws[WS_STATS + 2498 + ad*3 + bd];
        M2n[a][b] = v * (1.f/(float)MTOT);
    }
    if (t < 48) pmean[t] = (16.f*ws[WS_STATS + 2 + t] - ws[WS_STATS + 2507 + t%3])
                           * (1.f/(float)MTOT);
    if (t < DD) {
        for (int k = 0; k < 48; ++k) Wc[k][t] = posW1[(size_t)(i*48 + k)*DD + t];
    }
    __syncthreads();
    if (i == 0 && t < DD) {
        float dsum = ws[WS_STATS + 0];
        float dmax = __int_as_float(((const int*)(ws + WS_STATS))[1]);
        float vol = (dsum * (1.f/(float)MTOT)) / (dmax + 1e-8f);
        ws[WS_VOLV + t] = vol * gCW[t] + gCb[t];
    }
    if (t < DD) {
        float mu0 = 0.f;
        #pragma unroll 8
        for (int k = 0; k < 48; ++k) mu0 += pmean[k] * Wc[k][t];
        float e2 = 0.f;
        for (int a2 = 0; a2 < 48; ++a2) {
            float inner = 0.f;
            #pragma unroll 8
            for (int b2 = 0; b2 < 48; ++b2) inner += M2n[a2][b2] * Wc[b2][t];
            e2 += Wc[a2][t] * inner;
        }
        float var = fmaxf(e2 - mu0*mu0, 0.f);
        float as = rsqrtf(var + 1e-5f) * gamma[i*DD + t];
        ws[WS_AB + i*DD + t]       = as;
        ws[WS_AB + 576 + i*DD + t] = beta[i*DD + t] - mu0 * as;   // h'=relu(acc*as+bb)
    }
}

// ---- K_prop MFMA ----
__global__ __launch_bounds__(256) void k_prop_mfma(
    const float* __restrict__ x, const int* __restrict__ knn,
    const float* __restrict__ propW, const float* __restrict__ propB,
    float* __restrict__ ws)
{
    __shared__ ushort_t As[64*40];
    __shared__ ushort_t Bs[192*40];
    __shared__ float prs[64*3];
    __shared__ float W3[3*192];
    __shared__ int idx64[64];
    const int t = threadIdx.x;
    const int mbase = blockIdx.x * 64;
    const ushort_t* xb = (const ushort_t*)(ws + WS_XB);
    const ushort_t* pwt = (const ushort_t*)(ws + WS_PROPWT);
    if (t < 64) idx64[t] = knn[mbase + t];
    for (int e = t; e < 576; e += 256) W3[e] = propW[(size_t)(192 + e/192)*DD + (e % 192)];
    for (int e = t; e < 192; e += 256) prs[e] = ws[WS_PR + (size_t)mbase*3 + e];
    const int wave = t >> 6, lane = t & 63, m = lane & 15, quad = lane >> 4;
    f32x4 acc[12];
    #pragma unroll
    for (int nt = 0; nt < 12; ++nt) acc[nt] = (f32x4){0.f,0.f,0.f,0.f};
    for (int ks = 0; ks < 6; ++ks) {
        const int k0 = ks*32;
        __syncthreads();
        {   int r = t >> 2, seg = t & 3;
            *(uint4*)&As[r*40 + seg*8] = *(const uint4*)(xb + (size_t)idx64[r]*192 + k0 + seg*8);
        }
        for (int e = t; e < 768; e += 256) {
            int n = e >> 2, seg = e & 3;
            *(uint4*)&Bs[n*40 + seg*8] = *(const uint4*)(pwt + (size_t)n*192 + k0 + seg*8);
        }
        __syncthreads();
        short8 a = *(const short8*)&As[(wave*16 + m)*40 + quad*8];
        #pragma unroll
        for (int nt = 0; nt < 12; ++nt) {
            short8 b = *(const short8*)&Bs[(nt*16 + m)*40 + quad*8];
            acc[nt] = __builtin_amdgcn_mfma_f32_16x16x32_bf16(a, b, acc[nt], 0, 0, 0);
        }
    }
    const int n = blockIdx.x*4 + wave;
    #pragma unroll
    for (int nt = 0; nt < 12; ++nt) {
        int col = nt*16 + m;
        float bv = propB[col];
        float w0 = W3[col], w1 = W3[192 + col], w2 = W3[384 + col];
        float s = 0.f;
        #pragma unroll
        for (int reg = 0; reg < 4; ++reg) {
            int j = wave*16 + quad*4 + reg;
            float v = acc[nt][reg] + prs[j*3+0]*w0 + prs[j*3+1]*w1 + prs[j*3+2]*w2 + bv;
            s += fmaxf(v, 0.f);
        }
        s += __shfl_xor(s, 16);
        s += __shfl_xor(s, 32);
        if (quad == 0)
            ws[WS_X1 + (size_t)n*DD + col] = x[(size_t)n*DD + col] + s * (1.f/16.f);
    }
}

// ---- generic bf16 MFMA GEMM ----
__global__ __launch_bounds__(256) void gemm_mfma(
    const ushort_t* __restrict__ A, const ushort_t* __restrict__ Bt,
    const float* __restrict__ bias, float* __restrict__ Cf,
    ushort_t* __restrict__ Cb, int N)
{
    __shared__ ushort_t As[64*40];
    __shared__ ushort_t Bs[64*40];
    const int t = threadIdx.x;
    const int wave = t >> 6, lane = t & 63, m = lane & 15, quad = lane >> 4;
    const int rowBase = blockIdx.x * 64, colBase = blockIdx.y * 64;
    f32x4 acc[4];
    #pragma unroll
    for (int nt = 0; nt < 4; ++nt) acc[nt] = (f32x4){0.f,0.f,0.f,0.f};
    for (int ks = 0; ks < 6; ++ks) {
        __syncthreads();
        {   int r = t >> 2, seg = t & 3;
            *(uint4*)&As[r*40 + seg*8] = *(const uint4*)(A + (size_t)(rowBase + r)*192 + ks*32 + seg*8);
            *(uint4*)&Bs[r*40 + seg*8] = *(const uint4*)(Bt + (size_t)(colBase + r)*192 + ks*32 + seg*8);
        }
        __syncthreads();
        short8 a = *(const short8*)&As[(wave*16 + m)*40 + quad*8];
        #pragma unroll
        for (int nt = 0; nt < 4; ++nt) {
            short8 b = *(const short8*)&Bs[(nt*16 + m)*40 + quad*8];
            acc[nt] = __builtin_amdgcn_mfma_f32_16x16x32_bf16(a, b, acc[nt], 0, 0, 0);
        }
    }
    #pragma unroll
    for (int nt = 0; nt < 4; ++nt) {
        int col = colBase + nt*16 + m;
        float bv = bias ? bias[col] : 0.f;
        #pragma unroll
        for (int reg = 0; reg < 4; ++reg) {
            int row = rowBase + wave*16 + quad*4 + reg;
            float v = acc[nt][reg] + bv;
            if (Cf) Cf[(size_t)row*N + col] = v;
            else    Cb[(size_t)row*N + col] = f2bf(v);
        }
    }
}

// ---- K3a v2: keypoint attention via MFMA (8 points/block) + U assembly ----
__global__ __launch_bounds__(256) void k3a(
    const float* __restrict__ p, const float* __restrict__ kn,
    const float* __restrict__ deW1, const float* __restrict__ deB1,
    const float* __restrict__ deB2, const float* __restrict__ kpW,
    const float* __restrict__ gAW, const float* __restrict__ gAb,
    const float* __restrict__ gBW, const float* __restrict__ gBb,
    float* __restrict__ ws)
{
    __shared__ ushort_t fb[128*72];     // f rows bf16, K pad 64, stride 72
    __shared__ float kds[8][16];
    __shared__ float w1s[48], b1s[48];
    __shared__ float dfeat[8][192];
    ushort_t* ub = (ushort_t*)(ws + WS_UB);
    const int t = threadIdx.x;
    const int nb = blockIdx.x * 8;
    if (t < 48) { w1s[t] = deW1[t]; b1s[t] = deB1[t]; }
    if (t < 128) {
        int w = t >> 4, kp = t & 15;
        float dx = p[(nb+w)*3+0]-kn[kp*3+0];
        float dy = p[(nb+w)*3+1]-kn[kp*3+1];
        float dz = p[(nb+w)*3+2]-kn[kp*3+2];
        kds[w][kp] = sqrtf(dx*dx + dy*dy + dz*dz + 1e-12f);
    }
    __syncthreads();
    for (int e = t; e < 128*64; e += 256) {   // f = relu(kd*w1+b1), bf16 A tile
        int j = e >> 6, k = e & 63;
        float v = (k < 48) ? fmaxf(kds[j>>4][j&15]*w1s[k] + b1s[k], 0.f) : 0.f;
        fb[j*72 + k] = f2bf(v);
    }
    __syncthreads();
    const int wave = t >> 6, lane = t & 63, m = lane & 15, quad = lane >> 4;
    const ushort_t* dwt = (const ushort_t*)(ws + WS_DEW2T);
    short8 afr[2][2];
    #pragma unroll
    for (int mt = 0; mt < 2; ++mt)
        #pragma unroll
        for (int ks = 0; ks < 2; ++ks)
            afr[mt][ks] = *(const short8*)&fb[((wave*2 + mt)*16 + m)*72 + ks*32 + quad*8];
    float df[2][12][4];
    float sc[2][4];
    #pragma unroll
    for (int mt = 0; mt < 2; ++mt)
        #pragma unroll
        for (int reg = 0; reg < 4; ++reg) sc[mt][reg] = 0.f;
    for (int nt = 0; nt < 12; ++nt) {
        f32x4 acc0 = (f32x4){0.f,0.f,0.f,0.f};
        f32x4 acc1 = (f32x4){0.f,0.f,0.f,0.f};
        #pragma unroll
        for (int ks = 0; ks < 2; ++ks) {
            short8 b = *(const short8*)(dwt + ((size_t)(nt*16 + m)*64 + ks*32 + quad*8));
            acc0 = __builtin_amdgcn_mfma_f32_16x16x32_bf16(afr[0][ks], b, acc0, 0, 0, 0);
            acc1 = __builtin_amdgcn_mfma_f32_16x16x32_bf16(afr[1][ks], b, acc1, 0, 0, 0);
        }
        int col = nt*16 + m;
        float b2 = deB2[col], kw = kpW[col];
        #pragma unroll
        for (int reg = 0; reg < 4; ++reg) {
            float d0 = acc0[reg] + b2, d1 = acc1[reg] + b2;
            df[0][nt][reg] = d0; df[1][nt][reg] = d1;
            sc[0][reg] += d0*kw; sc[1][reg] += d1*kw;
        }
    }
    #pragma unroll
    for (int mt = 0; mt < 2; ++mt)     // reduce score over m lanes (width 16)
        #pragma unroll
        for (int reg = 0; reg < 4; ++reg) {
            float v = sc[mt][reg];
            v += __shfl_xor(v, 1, 16); v += __shfl_xor(v, 2, 16);
            v += __shfl_xor(v, 4, 16); v += __shfl_xor(v, 8, 16);
            sc[mt][reg] = v;
        }
    float wgt[2][4];
    #pragma unroll
    for (int mt = 0; mt < 2; ++mt) {   // softmax over kp = quad*4+reg (kpB const: dropped)
        float mx = fmaxf(fmaxf(sc[mt][0], sc[mt][1]), fmaxf(sc[mt][2], sc[mt][3]));
        mx = fmaxf(mx, __shfl_xor(mx, 16));
        mx = fmaxf(mx, __shfl_xor(mx, 32));
        float sm = 0.f;
        #pragma unroll
        for (int reg = 0; reg < 4; ++reg) { wgt[mt][reg] = expf(sc[mt][reg] - mx); sm += wgt[mt][reg]; }
        sm += __shfl_xor(sm, 16);
        sm += __shfl_xor(sm, 32);
        float inv = 1.f / sm;
        #pragma unroll
        for (int reg = 0; reg < 4; ++reg) wgt[mt][reg] *= inv;
    }
    for (int nt = 0; nt < 12; ++nt) {  // dfeat = attn-weighted kp-reduction
        int col = nt*16 + m;
        #pragma unroll
        for (int mt = 0; mt < 2; ++mt) {
            float s = 0.f;
            #pragma unroll
            for (int reg = 0; reg < 4; ++reg) s += wgt[mt][reg] * df[mt][nt][reg];
            s += __shfl_xor(s, 16);
            s += __shfl_xor(s, 32);
            if (quad == 0) dfeat[wave*2 + mt][col] = s;
        }
    }
    __syncthreads();
    if (t < DD) {                      // U assembly -> bf16 UB
        for (int w = 0; w < 8; ++w) {
            int n = nb + w;
            float uval = ws[WS_X1 + (size_t)n*DD + t] + gAb[t] + gBb[t]
                       + ws[WS_VOLV + t] + dfeat[w][t];
            uval += ws[WS_GDIS + n] * gBW[t];
            #pragma unroll
            for (int kk = 0; kk < 9; ++kk) uval += ws[WS_GEO9 + (size_t)n*9 + kk] * gAW[kk*DD + t];
            ub[(size_t)n*DD + t] = f2bf(uval);
        }
    }
}

// ---- K_attn_fused: 8 windows/block, 38.9KB LDS -> 4 blocks/CU ----
// posb eliminated (A-fragments computed into registers from Xl);
// rqs/wsum stored bf16 (36.9KB -> 18.4KB).
__global__ __launch_bounds__(256, 4) void k_attn_fused(
    const int* __restrict__ knn,
    const float* __restrict__ posW2, const float* __restrict__ posB2,
    float* __restrict__ ws)
{
    __shared__ ushort_t rqs[8*6*192];   // bf16 rq per i; later bf16 wsum
    __shared__ float qk[8*192];         // q0 (i=0) / k0 (i=1), reloaded per i
    __shared__ float scb[8*192];        // sc[w][i(2)][h(6)][j(16)]
    __shared__ float dqk[8*96];         // dqk[w][h][j]
    __shared__ float attns[8*96];
    __shared__ float Xl[8][48];
    __shared__ int idxs[128];
    const int t = threadIdx.x;
    const int nb = blockIdx.x * 8;
    ushort_t* ctrb = (ushort_t*)(ws + WS_CTRB);
    const ushort_t* qkvb = (const ushort_t*)(ws + WS_QKV);
    if (t < 128) idxs[t] = knn[(nb + (t >> 4))*NS + (t & 15)];
    for (int e = t; e < 384; e += 256) {
        int w = e/48, k = e%48;
        Xl[w][k] = ws[WS_KNN + (size_t)(nb+w)*48 + k];
    }
    __syncthreads();
    const int wave = t >> 6, lane = t & 63, m = lane & 15, quad = lane >> 4;
    // pos A-fragments: row j=(wave*2+mt)*16+m, col k=ks*32+quad*8+e
    // pos[j][k] = Xl[w][k] - Xl[w][(j&15)*3 + k%3], zero-padded past 48
    short8 afr[2][2];
    #pragma unroll
    for (int mt = 0; mt < 2; ++mt) {
        const int w = wave*2 + mt;
        #pragma unroll
        for (int ks = 0; ks < 2; ++ks) {
            short8 v;
            #pragma unroll
            for (int e = 0; e < 8; ++e) {
                const int k = ks*32 + quad*8 + e;
                float f = (k < 48) ? (Xl[w][k] - Xl[w][m*3 + (k % 3)]) : 0.f;
                v[e] = (short)f2bf(f);
            }
            afr[mt][ks] = v;
        }
    }
    const ushort_t* w1t = (const ushort_t*)(ws + WS_W1T);
    // ---- i = 0,1: rq + MFMA H + fused contraction -> scb ----
    for (int i = 0; i < 2; ++i) {
        __syncthreads();   // prior rqs,qk readers done
        for (int e = t; e < 8*192; e += 256) {
            int w = e/192, c = e%192;
            qk[e] = bf2f(qkvb[(size_t)idxs[w*16]*576 + i*192 + c]);
        }
        __syncthreads();
        if (t < 192) {     // rq: W2 row t (global) x qk broadcast
            const float* Wrow = posW2 + (size_t)i*DD*DD + (size_t)t*DD;
            for (int h = 0; h < 6; ++h) {
                float4 wr[8];
                #pragma unroll
                for (int q = 0; q < 8; ++q) wr[q] = *(const float4*)(Wrow + h*32 + q*4);
                float a[8];
                #pragma unroll
                for (int w = 0; w < 8; ++w) a[w] = 0.f;
                #pragma unroll
                for (int q = 0; q < 8; ++q) {
                    #pragma unroll
                    for (int d = 0; d < 4; ++d) {
                        float wv = (&wr[q].x)[d];
                        int c = h*32 + q*4 + d;
                        #pragma unroll
                        for (int w = 0; w < 8; ++w) a[w] += wv * qk[w*192 + c];
                    }
                }
                #pragma unroll
                for (int w = 0; w < 8; ++w) rqs[(w*6 + h)*192 + t] = f2bf(a[w]);
            }
        }
        __syncthreads();
        float s[48];       // [mt(2)][reg(4)][h(6)]
        #pragma unroll
        for (int e = 0; e < 48; ++e) s[e] = 0.f;
        for (int nt = 0; nt < 12; ++nt) {
            f32x4 acc0 = (f32x4){0.f,0.f,0.f,0.f};
            f32x4 acc1 = (f32x4){0.f,0.f,0.f,0.f};
            #pragma unroll
            for (int ks = 0; ks < 2; ++ks) {
                short8 b = *(const short8*)(w1t + ((size_t)(i*192 + nt*16 + m)*64 + ks*32 + quad*8));
                acc0 = __builtin_amdgcn_mfma_f32_16x16x32_bf16(afr[0][ks], b, acc0, 0, 0, 0);
                acc1 = __builtin_amdgcn_mfma_f32_16x16x32_bf16(afr[1][ks], b, acc1, 0, 0, 0);
            }
            int kk = nt*16 + m;
            float as = ws[WS_AB + i*DD + kk];
            float bb = ws[WS_AB + 576 + i*DD + kk];
            float h0[4], h1[4];
            #pragma unroll
            for (int reg = 0; reg < 4; ++reg) {
                h0[reg] = fmaxf(acc0[reg]*as + bb, 0.f);
                h1[reg] = fmaxf(acc1[reg]*as + bb, 0.f);
            }
            #pragma unroll
            for (int h = 0; h < 6; ++h) {
                float r0 = bf2f(rqs[((wave*2 + 0)*6 + h)*192 + kk]);
                float r1 = bf2f(rqs[((wave*2 + 1)*6 + h)*192 + kk]);
                #pragma unroll
                for (int reg = 0; reg < 4; ++reg) {
                    s[reg*6 + h]      += h0[reg]*r0;
                    s[24 + reg*6 + h] += h1[reg]*r1;
                }
            }
        }
        #pragma unroll
        for (int e = 0; e < 48; ++e) {
            float v = s[e];
            v += __shfl_xor(v, 1, 16); v += __shfl_xor(v, 2, 16);
            v += __shfl_xor(v, 4, 16); v += __shfl_xor(v, 8, 16);
            s[e] = v;
        }
        if (m == 0) {
            #pragma unroll
            for (int mt = 0; mt < 2; ++mt)
                #pragma unroll
                for (int reg = 0; reg < 4; ++reg) {
                    int w = wave*2 + mt, j = quad*4 + reg;
                    #pragma unroll
                    for (int h = 0; h < 6; ++h)
                        scb[w*192 + i*96 + h*16 + j] = s[mt*24 + reg*6 + h];
                }
        }
    }
    // ---- dqk dots: thread -> (w, j, half); bf16 rows ----
    {
        const int w = t >> 5, r = t & 31, j = r >> 1, half = r & 1;
        const ushort_t* krow = qkvb + (size_t)idxs[w*16 + j]*576 + 192 + half*96;
        const ushort_t* qrow = qkvb + (size_t)idxs[w*16]*576 + half*96;
        float hd[3] = {0.f, 0.f, 0.f};
        #pragma unroll
        for (int q = 0; q < 12; ++q) {
            uint4 kv = *(const uint4*)(krow + q*8);
            uint4 qv = *(const uint4*)(qrow + q*8);
            float sv = 0.f;
            #pragma unroll
            for (int d = 0; d < 4; ++d) {
                unsigned int ku = (&kv.x)[d], qu = (&qv.x)[d];
                sv += __uint_as_float(ku << 16) * __uint_as_float(qu << 16);
                sv += __uint_as_float(ku & 0xffff0000u) * __uint_as_float(qu & 0xffff0000u);
            }
            hd[q >> 2] += sv;
        }
        dqk[w*96 + (half*3+0)*16 + j] = hd[0];
        dqk[w*96 + (half*3+1)*16 + j] = hd[1];
        dqk[w*96 + (half*3+2)*16 + j] = hd[2];
    }
    __syncthreads();   // dqk+scb ready; also all rqs reads (i=1) done
    // ---- softmax over j per (w,h) ----
    {
        const float scale = 0.17677669529663687f;  // 32^-0.5
        #pragma unroll
        for (int c = 0; c < 3; ++c) {
            int e = c*256 + t;
            int row = e >> 4, j = e & 15, w = row / 6, h = row % 6;
            float z = (dqk[e] + scb[w*192 + h*16 + j] + scb[w*192 + 96 + h*16 + j]) * scale;
            float mx = z;
            #pragma unroll
            for (int off = 1; off < 16; off <<= 1) mx = fmaxf(mx, __shfl_xor(mx, off, 16));
            float ex = expf(z - mx);
            float sm = ex;
            #pragma unroll
            for (int off = 1; off < 16; off <<= 1) sm += __shfl_xor(sm, off, 16);
            attns[w*96 + h*16 + j] = ex / sm;
        }
    }
    __syncthreads();   // attns ready
    // ---- ctr1 = attn @ v (bf16 V rows) ----
    float ctr1[8];
    if (t < DD) {
        const int h = t >> 5;
        #pragma unroll
        for (int w = 0; w < 8; ++w) {
            float sv = 0.f;
            #pragma unroll
            for (int j = 0; j < NS; ++j)
                sv += attns[w*96 + h*16 + j] * bf2f(qkvb[(size_t)idxs[w*16 + j]*576 + 384 + t]);
            ctr1[w] = sv;
        }
    }
    // ---- H2 MFMA + attn-weighted reduce -> bf16 wsum (rqs region) ----
    {
        ushort_t* wsum = rqs;
        const int w0 = wave*2, w1 = wave*2 + 1;
        for (int nt = 0; nt < 12; ++nt) {
            f32x4 acc0 = (f32x4){0.f,0.f,0.f,0.f};
            f32x4 acc1 = (f32x4){0.f,0.f,0.f,0.f};
            #pragma unroll
            for (int ks = 0; ks < 2; ++ks) {
                short8 b = *(const short8*)(w1t + ((size_t)(2*192 + nt*16 + m)*64 + ks*32 + quad*8));
                acc0 = __builtin_amdgcn_mfma_f32_16x16x32_bf16(afr[0][ks], b, acc0, 0, 0, 0);
                acc1 = __builtin_amdgcn_mfma_f32_16x16x32_bf16(afr[1][ks], b, acc1, 0, 0, 0);
            }
            int kk = nt*16 + m;
            float as = ws[WS_AB + 2*DD + kk];
            float bb = ws[WS_AB + 576 + 2*DD + kk];
            float h0[4], h1[4];
            #pragma unroll
            for (int reg = 0; reg < 4; ++reg) {
                h0[reg] = fmaxf(acc0[reg]*as + bb, 0.f);
                h1[reg] = fmaxf(acc1[reg]*as + bb, 0.f);
            }
            #pragma unroll
            for (int h = 0; h < 6; ++h) {
                float p0 = 0.f, p1 = 0.f;
                #pragma unroll
                for (int reg = 0; reg < 4; ++reg) {
                    int j = quad*4 + reg;
                    p0 += attns[w0*96 + h*16 + j] * h0[reg];
                    p1 += attns[w1*96 + h*16 + j] * h1[reg];
                }
                p0 += __shfl_xor(p0, 16); p0 += __shfl_xor(p0, 32);
                p1 += __shfl_xor(p1, 16); p1 += __shfl_xor(p1, 32);
                if (quad == 0) {
                    wsum[(w0*6 + h)*192 + kk] = f2bf(p0);
                    wsum[(w1*6 + h)*192 + kk] = f2bf(p1);
                }
            }
        }
    }
    __syncthreads();   // wsum ready
    // ---- pv = wsum @ W2_2 via W2T rows; CTR = ctr1 + pv + b2 ----
    if (t < DD) {
        const ushort_t* wsum = rqs;
        const int h = t >> 5;
        float pvacc[8];
        #pragma unroll
        for (int w = 0; w < 8; ++w) pvacc[w] = 0.f;
        const float* wrow = ws + WS_W2T + (size_t)t*DD;
        for (int k4 = 0; k4 < 48; ++k4) {
            float4 wv = *(const float4*)(wrow + k4*4);
            #pragma unroll
            for (int w = 0; w < 8; ++w) {
                const ushort_t* av = &wsum[(w*6 + h)*192 + k4*4];
                pvacc[w] += bf2f(av[0])*wv.x + bf2f(av[1])*wv.y
                          + bf2f(av[2])*wv.z + bf2f(av[3])*wv.w;
            }
        }
        float b2 = posB2[2*DD + t];
        #pragma unroll
        for (int w = 0; w < 8; ++w)
            ctrb[(size_t)(nb+w)*DD + t] = f2bf(ctr1[w] + pvacc[w] + b2);
    }
}

extern "C" void kernel_launch(void* const* d_in, const int* in_sizes, int n_in,
                              void* d_out, int out_size, void* d_ws, size_t ws_size,
                              hipStream_t stream)
{
    const float* p     = (const float*)d_in[0];
    const float* x     = (const float*)d_in[1];
    const int*   knn   = (const int*)  d_in[2];
    const float* Wqkv  = (const float*)d_in[3];
    const float* Wproj = (const float*)d_in[4];
    const float* bproj = (const float*)d_in[5];
    const float* propW = (const float*)d_in[6];
    const float* propB = (const float*)d_in[7];
    const float* gAW   = (const float*)d_in[8];
    const float* gAb   = (const float*)d_in[9];
    const float* gBW   = (const float*)d_in[10];
    const float* gBb   = (const float*)d_in[11];
    const float* gCW   = (const float*)d_in[12];
    const float* gCb   = (const float*)d_in[13];
    const float* posW1 = (const float*)d_in[14];
    const float* posB1 = (const float*)d_in[15];
    const float* gamma = (const float*)d_in[16];
    const float* beta  = (const float*)d_in[17];
    const float* posW2 = (const float*)d_in[18];
    const float* posB2 = (const float*)d_in[19];
    const float* kn    = (const float*)d_in[20];
    const float* deW1  = (const float*)d_in[21];
    const float* deB1  = (const float*)d_in[22];
    const float* deW2  = (const float*)d_in[23];
    const float* deB2  = (const float*)d_in[24];
    const float* kpW   = (const float*)d_in[25];
    const float* kpB   = (const float*)d_in[26];
    const float* fusW  = (const float*)d_in[27];
    const float* fusB  = (const float*)d_in[28];
    float* ws   = (float*)d_ws;
    float* outp = (float*)d_out;
    (void)kpB;  // constant shift inside softmax: invariant, dropped

    hipLaunchKernelGGL(k_init, dim3(10), dim3(256), 0, stream, ws);
    hipLaunchKernelGGL(k_w2t, dim3(144), dim3(256), 0, stream, posW2, ws);
    hipLaunchKernelGGL(k_prep, dim3(1056), dim3(256), 0, stream,
                       propW, Wqkv, fusW, Wproj, posW1, deW2, ws);
    hipLaunchKernelGGL(k_castx, dim3(NP*DD/256), dim3(256), 0, stream, x, ws);
    hipLaunchKernelGGL(k1a_geom, dim3(NP/16), dim3(256), 0, stream, p, knn, ws);
    hipLaunchKernelGGL(k1b_stats, dim3(NP/128), dim3(256), 0, stream, ws);
    hipLaunchKernelGGL(k2_fold, dim3(3), dim3(256), 0, stream,
                       posW1, posB1, gamma, beta, gCW, gCb, ws);
    hipLaunchKernelGGL(k_prop_mfma, dim3(MTOT/64), dim3(256), 0, stream,
                       x, knn, propW, propB, ws);
    hipLaunchKernelGGL(k3a, dim3(NP/8), dim3(256), 0, stream,
                       p, kn, deW1, deB1, deB2, kpW, gAW, gAb, gBW, gBb, ws);
    // X2B = bf16(UB @ fusW + fusB)
    hipLaunchKernelGGL(gemm_mfma, dim3(NP/64, 3), dim3(256), 0, stream,
                       (const ushort_t*)(ws + WS_UB), (const ushort_t*)(ws + WS_FUSWT),
                       fusB, (float*)nullptr, (ushort_t*)(ws + WS_X2B), DD);
    // QKV = bf16(X2B @ Wqkv)
    hipLaunchKernelGGL(gemm_mfma, dim3(NP/64, 9), dim3(256), 0, stream,
                       (const ushort_t*)(ws + WS_X2B), (const ushort_t*)(ws + WS_QKVT),
                       (const float*)nullptr, (float*)nullptr,
                       (ushort_t*)(ws + WS_QKV), 576);
    hipLaunchKernelGGL(k_attn_fused, dim3(NP/8), dim3(256), 0, stream,
                       knn, posW2, posB2, ws);
    // OUT = CTRB @ Wproj + bproj (fp32 out)
    hipLaunchKernelGGL(gemm_mfma, dim3(NP/64, 3), dim3(256), 0, stream,
                       (const ushort_t*)(ws + WS_CTRB), (const ushort_t*)(ws + WS_PROJWT),
                       bproj, outp, (ushort_t*)nullptr, DD);
}

// Round 4
// 578.031 us; speedup vs baseline: 1.2817x; 1.0573x over previous
//
#include <hip/hip_runtime.h>
#include <math.h>

#define NP 16384
#define DD 192
#define NS 16
#define KSPN 16
#define MTOT (NP*NS)

typedef unsigned short ushort_t;
typedef __attribute__((ext_vector_type(8))) short short8;
typedef __attribute__((ext_vector_type(4))) float f32x4;

__device__ __forceinline__ ushort_t f2bf(float f) {
    union { float f; unsigned int u; } v; v.f = f;
    return (ushort_t)((v.u + 0x7FFFu + ((v.u >> 16) & 1u)) >> 16);
}
__device__ __forceinline__ float bf2f(ushort_t u) {
    return __uint_as_float(((unsigned int)u) << 16);
}

// ws float offsets
#define WS_KNN   0                         // NP*48   knn_xyz
#define WS_PR    (WS_KNN + NP*48)          // MTOT*3  p_r per window row
#define WS_GEO9  (WS_PR + MTOT*3)          // NP*9
#define WS_GDIS  (WS_GEO9 + NP*9)          // NP
// STATS: [0]=dsum [1]=dmax(bits) [2..50)=sumX [50..2354)=A1 [2354..2498)=A2
//        [2498..2507)=A3 [2507..2510)=sumS
#define WS_STATS (WS_GDIS + NP)
#define WS_VOLV  (WS_STATS + 2512)         // 192
#define WS_AB    (WS_VOLV + DD)            // a[3][192] | bb[3][192] = 1152
#define WS_X1    (WS_AB + 1152)            // NP*192 post-propagate (consumed by k3a)
#define WS_U     (WS_X1 + NP*DD)           // NP*192: CTRB (bf16) after fused attn
#define WS_X2    (WS_U + NP*DD)            // NP*192: X2B (bf16, written by fus gemm)
#define WS_QKV   (WS_X2 + NP*DD)           // NP*576 bf16 (uses half the region)
#define WS_SC    (WS_QKV + NP*576)         // region: XB overlay (bf16 x) + w2b/w2t2b tail
#define WS_ATTN  (WS_SC + NP*DD)           // region: UB overlay (bf16 U)
#define WS_W2T   (WS_ATTN + NP*96)         // (legacy fp32 W2T slot, now unused)
#define WS_PROPWT (WS_W2T + 36864)         // 18432 floats (bf16 transposed propW[:192])
#define WS_QKVT  (WS_PROPWT + 18432)       // 55296
#define WS_FUSWT (WS_QKVT + 55296)         // 18432
#define WS_PROJWT (WS_FUSWT + 18432)       // 18432
#define WS_W1T   (WS_PROJWT + 18432)       // 3*192*64 bf16 = 18432 floats (K pad 64)
#define WS_DEW2T (WS_W1T + 18432)          // 192*64 bf16 = 6144 floats
// overlays (bf16 arrays in dead-interval regions):
#define WS_XB    WS_SC
#define WS_UB    WS_ATTN
#define WS_X2B   WS_X2
#define WS_CTRB  WS_U
// bf16 posW2 copies in the dead tail of the SC region (past XB's NP*96 floats):
#define WS_W2B   (WS_SC + NP*96)           // 73728 ushorts: bf16 posW2[0..1], row-major
#define WS_W2T2B (WS_W2B + 36864)          // 36864 ushorts: bf16 posW2[2]^T [t][k]

__global__ __launch_bounds__(256) void k_init(float* __restrict__ ws) {
    int t = blockIdx.x * 256 + threadIdx.x;
    if (t < 2512) ws[WS_STATS + t] = 0.f;
}

// ---- prep: bf16 transposed weight copies (n-major, k-contiguous) ----
__global__ __launch_bounds__(256) void k_prep(
    const float* __restrict__ propW, const float* __restrict__ Wqkv,
    const float* __restrict__ fusW, const float* __restrict__ Wproj,
    const float* __restrict__ posW1, const float* __restrict__ deW2,
    const float* __restrict__ posW2, float* __restrict__ ws)
{
    int e = blockIdx.x*256 + threadIdx.x;
    ushort_t* pwt = (ushort_t*)(ws + WS_PROPWT);
    ushort_t* qkt = (ushort_t*)(ws + WS_QKVT);
    ushort_t* fwt = (ushort_t*)(ws + WS_FUSWT);
    ushort_t* pjt = (ushort_t*)(ws + WS_PROJWT);
    ushort_t* w1t = (ushort_t*)(ws + WS_W1T);
    ushort_t* dwt = (ushort_t*)(ws + WS_DEW2T);
    ushort_t* w2b = (ushort_t*)(ws + WS_W2B);
    ushort_t* w2t2b = (ushort_t*)(ws + WS_W2T2B);
    if (e < 36864) {
        int n = e/192, k = e - n*192;
        pwt[e] = f2bf(propW[(size_t)k*192 + n]);
    } else if (e < 147456) {
        int r = e - 36864; int n = r/192, k = r - n*192;
        qkt[r] = f2bf(Wqkv[(size_t)k*576 + n]);
    } else if (e < 184320) {
        int r = e - 147456; int n = r/192, k = r - n*192;
        fwt[r] = f2bf(fusW[(size_t)k*192 + n]);
    } else if (e < 221184) {
        int r = e - 184320; int n = r/192, k = r - n*192;
        pjt[r] = f2bf(Wproj[(size_t)k*192 + n]);
    } else if (e < 258048) {
        int r = e - 221184;
        int i = r / 12288, rem = r - i*12288;
        int n = rem / 64, k = rem - n*64;
        w1t[r] = (k < 48) ? f2bf(posW1[(size_t)(i*48 + k)*DD + n]) : (ushort_t)0;
    } else if (e < 270336) {
        int r = e - 258048;
        int n = r / 64, k = r - n*64;
        dwt[r] = (k < 48) ? f2bf(deW2[(size_t)k*DD + n]) : (ushort_t)0;
    } else if (e < 344064) {
        int r = e - 270336;                // bf16 posW2[0..1], identical layout
        w2b[r] = f2bf(posW2[r]);
    } else if (e < 380928) {
        int r = e - 344064;                // w2t2b[t][k] = posW2[2][k][t]
        int tr = r / 192, k = r - tr*192;
        w2t2b[r] = f2bf(posW2[(size_t)2*36864 + (size_t)k*192 + tr]);
    }
}

// ---- cast x -> bf16 ----
__global__ __launch_bounds__(256) void k_castx(const float* __restrict__ x,
                                               float* __restrict__ ws) {
    int e = blockIdx.x*256 + threadIdx.x;
    ((ushort_t*)(ws + WS_XB))[e] = f2bf(x[e]);
}

// ---- K1a: per-(point,neighbor) geometry ----
__global__ __launch_bounds__(256) void k1a_geom(
    const float* __restrict__ p, const int* __restrict__ knn,
    float* __restrict__ ws)
{
    __shared__ float red[32];
    const int t = threadIdx.x;
    const int w = t >> 4, u = t & 15;
    const int n = blockIdx.x*16 + w;
    const int idx = knn[n*NS + u];
    const float X0 = p[idx*3+0], X1 = p[idx*3+1], X2 = p[idx*3+2];
    const float pn0 = p[n*3+0], pn1 = p[n*3+1], pn2 = p[n*3+2];
    ws[WS_KNN + (size_t)n*48 + u*3 + 0] = X0;
    ws[WS_KNN + (size_t)n*48 + u*3 + 1] = X1;
    ws[WS_KNN + (size_t)n*48 + u*3 + 2] = X2;
    const float dx = X0-pn0, dy = X1-pn1, dz = X2-pn2;
    ws[WS_PR + (size_t)(n*NS+u)*3 + 0] = dx;
    ws[WS_PR + (size_t)(n*NS+u)*3 + 1] = dy;
    ws[WS_PR + (size_t)(n*NS+u)*3 + 2] = dz;
    const float dist = sqrtf(dx*dx + dy*dy + dz*dz + 1e-12f);
    float dmx = dist, dsm = dist, S0 = X0, S1 = X1, S2 = X2;
    #pragma unroll
    for (int off = 1; off < 16; off <<= 1) {
        dmx = fmaxf(dmx, __shfl_xor(dmx, off, 16));
        dsm += __shfl_xor(dsm, off, 16);
        S0 += __shfl_xor(S0, off, 16);
        S1 += __shfl_xor(S1, off, 16);
        S2 += __shfl_xor(S2, off, 16);
    }
    if (u == 0) {
        ws[WS_GDIS + n] = dmx;
        float m0 = S0*(1.f/16.f), m1 = S1*(1.f/16.f), m2 = S2*(1.f/16.f);
        float* g = ws + WS_GEO9 + (size_t)n*9;
        g[0] = m0-pn0; g[1] = m1-pn1; g[2] = m2-pn2;
        g[3] = m0; g[4] = m1; g[5] = m2;
        g[6] = pn0; g[7] = pn1; g[8] = pn2;
        red[w] = dsm; red[16+w] = dmx;
    }
    __syncthreads();
    if (t == 0) {
        float ds = 0.f, dm = 0.f;
        #pragma unroll
        for (int i = 0; i < 16; ++i) { ds += red[i]; dm = fmaxf(dm, red[16+i]); }
        atomicAdd(&ws[WS_STATS + 0], ds);
        atomicMax((int*)(ws + WS_STATS + 1), __float_as_int(dm));  // dist>=0
    }
}

// ---- K1b: factored BN stats ----
__global__ __launch_bounds__(256) void k1b_stats(float* __restrict__ ws)
{
    __shared__ float Xs[128][48];
    __shared__ float Ss[128][3];
    __shared__ float a3p[9][16];
    const int t = threadIdx.x;
    const int c0 = blockIdx.x * 128;
    for (int e = t; e < 1536; e += 256) {
        int r = e/12, q = e%12;
        *(float4*)&Xs[r][q*4] = *(const float4*)(ws + WS_KNN + (size_t)(c0+r)*48 + q*4);
    }
    __syncthreads();
    if (t < 128) {
        float s0 = 0.f, s1 = 0.f, s2 = 0.f;
        #pragma unroll
        for (int j = 0; j < 16; ++j) { s0 += Xs[t][3*j]; s1 += Xs[t][3*j+1]; s2 += Xs[t][3*j+2]; }
        Ss[t][0] = s0; Ss[t][1] = s1; Ss[t][2] = s2;
    }
    __syncthreads();
    {
        float acc[9];
        #pragma unroll
        for (int q = 0; q < 9; ++q) acc[q] = 0.f;
        for (int i = 0; i < 128; ++i) {
            int e = t;
            #pragma unroll
            for (int q = 0; q < 9; ++q) {
                int a = e/48, b = e%48;
                acc[q] += Xs[i][a] * Xs[i][b];
                e += 256;
            }
        }
        int e = t;
        #pragma unroll
        for (int q = 0; q < 9; ++q) { atomicAdd(&ws[WS_STATS + 50 + e], acc[q]); e += 256; }
    }
    if (t < 144) {
        int a = t/3, d = t%3;
        float s = 0.f;
        for (int i = 0; i < 128; ++i) s += Xs[i][a] * Ss[i][d];
        atomicAdd(&ws[WS_STATS + 2354 + t], s);
    }
    if (t < 144) {
        int q = t >> 4, part = t & 15;
        int d = q/3, e2 = q%3;
        float s = 0.f;
        for (int i = part*8; i < part*8 + 8; ++i) {
            #pragma unroll
            for (int j = 0; j < 16; ++j) s += Xs[i][3*j+d] * Xs[i][3*j+e2];
        }
        a3p[q][part] = s;
    }
    if (t < 48) {
        float s = 0.f;
        for (int i = 0; i < 128; ++i) s += Xs[i][t];
        atomicAdd(&ws[WS_STATS + 2 + t], s);
    }
    if (t < 3) {
        float s = 0.f;
        for (int i = 0; i < 128; ++i) s += Ss[i][t];
        atomicAdd(&ws[WS_STATS + 2507 + t], s);
    }
    __syncthreads();
    if (t < 9) {
        float s = 0.f;
        #pragma unroll
        for (int i = 0; i < 16; ++i) s += a3p[t][i];
        atomicAdd(&ws[WS_STATS + 2498 + t], s);
    }
}

// ---- K2: vol vector + BN fold (M2 reconstructed from factored stats) ----
__global__ __launch_bounds__(256) void k2_fold(
    const float* __restrict__ posW1, const float* __restrict__ posB1,
    const float* __restrict__ gamma, const float* __restrict__ beta,
    const float* __restrict__ gCW, const float* __restrict__ gCb,
    float* __restrict__ ws)
{
    __shared__ float M2n[48][48];
    __shared__ float pmean[48];
    __shared__ float Wc[48][193];
    const int t = threadIdx.x;
    const int i = blockIdx.x;
    for (int e = t; e < 2304; e += 256) {
        int a = e/48, b = e%48, ad = a%3, bd = b%3;
        float v = 16.f*ws[WS_STATS + 50 + e]
                - ws[WS_STATS + 2354 + a*3 + bd]
                - ws[WS_STATS + 2354 + b*3 + ad]
                + ws[WS_STATS + 2498 + ad*3 + bd];
        M2n[a][b] = v * (1.f/(float)MTOT);
    }
    if (t < 48) pmean[t] = (16.f*ws[WS_STATS + 2 + t] - ws[WS_STATS + 2507 + t%3])
                           * (1.f/(float)MTOT);
    if (t < DD) {
        for (int k = 0; k < 48; ++k) Wc[k][t] = posW1[(size_t)(i*48 + k)*DD + t];
    }
    __syncthreads();
    if (i == 0 && t < DD) {
        float dsum = ws[WS_STATS + 0];
        float dmax = __int_as_float(((const int*)(ws + WS_STATS))[1]);
        float vol = (dsum * (1.f/(float)MTOT)) / (dmax + 1e-8f);
        ws[WS_VOLV + t] = vol * gCW[t] + gCb[t];
    }
    if (t < DD) {
        float mu0 = 0.f;
        #pragma unroll 8
        for (int k = 0; k < 48; ++k) mu0 += pmean[k] * Wc[k][t];
        float e2 = 0.f;
        for (int a2 = 0; a2 < 48; ++a2) {
            float inner = 0.f;
            #pragma unroll 8
            for (int b2 = 0; b2 < 48; ++b2) inner += M2n[a2][b2] * Wc[b2][t];
            e2 += Wc[a2][t] * inner;
        }
        float var = fmaxf(e2 - mu0*mu0, 0.f);
        float as = rsqrtf(var + 1e-5f) * gamma[i*DD + t];
        ws[WS_AB + i*DD + t]       = as;
        ws[WS_AB + 576 + i*DD + t] = beta[i*DD + t] - mu0 * as;   // h'=relu(acc*as+bb)
    }
}

// ---- K_prop MFMA ----
__global__ __launch_bounds__(256) void k_prop_mfma(
    const float* __restrict__ x, const int* __restrict__ knn,
    const float* __restrict__ propW, const float* __restrict__ propB,
    float* __restrict__ ws)
{
    __shared__ ushort_t As[64*40];
    __shared__ ushort_t Bs[192*40];
    __shared__ float prs[64*3];
    __shared__ float W3[3*192];
    __shared__ int idx64[64];
    const int t = threadIdx.x;
    const int mbase = blockIdx.x * 64;
    const ushort_t* xb = (const ushort_t*)(ws + WS_XB);
    const ushort_t* pwt = (const ushort_t*)(ws + WS_PROPWT);
    if (t < 64) idx64[t] = knn[mbase + t];
    for (int e = t; e < 576; e += 256) W3[e] = propW[(size_t)(192 + e/192)*DD + (e % 192)];
    for (int e = t; e < 192; e += 256) prs[e] = ws[WS_PR + (size_t)mbase*3 + e];
    const int wave = t >> 6, lane = t & 63, m = lane & 15, quad = lane >> 4;
    f32x4 acc[12];
    #pragma unroll
    for (int nt = 0; nt < 12; ++nt) acc[nt] = (f32x4){0.f,0.f,0.f,0.f};
    for (int ks = 0; ks < 6; ++ks) {
        const int k0 = ks*32;
        __syncthreads();
        {   int r = t >> 2, seg = t & 3;
            *(uint4*)&As[r*40 + seg*8] = *(const uint4*)(xb + (size_t)idx64[r]*192 + k0 + seg*8);
        }
        for (int e = t; e < 768; e += 256) {
            int n = e >> 2, seg = e & 3;
            *(uint4*)&Bs[n*40 + seg*8] = *(const uint4*)(pwt + (size_t)n*192 + k0 + seg*8);
        }
        __syncthreads();
        short8 a = *(const short8*)&As[(wave*16 + m)*40 + quad*8];
        #pragma unroll
        for (int nt = 0; nt < 12; ++nt) {
            short8 b = *(const short8*)&Bs[(nt*16 + m)*40 + quad*8];
            acc[nt] = __builtin_amdgcn_mfma_f32_16x16x32_bf16(a, b, acc[nt], 0, 0, 0);
        }
    }
    const int n = blockIdx.x*4 + wave;
    #pragma unroll
    for (int nt = 0; nt < 12; ++nt) {
        int col = nt*16 + m;
        float bv = propB[col];
        float w0 = W3[col], w1 = W3[192 + col], w2 = W3[384 + col];
        float s = 0.f;
        #pragma unroll
        for (int reg = 0; reg < 4; ++reg) {
            int j = wave*16 + quad*4 + reg;
            float v = acc[nt][reg] + prs[j*3+0]*w0 + prs[j*3+1]*w1 + prs[j*3+2]*w2 + bv;
            s += fmaxf(v, 0.f);
        }
        s += __shfl_xor(s, 16);
        s += __shfl_xor(s, 32);
        if (quad == 0)
            ws[WS_X1 + (size_t)n*DD + col] = x[(size_t)n*DD + col] + s * (1.f/16.f);
    }
}

// ---- generic bf16 MFMA GEMM ----
__global__ __launch_bounds__(256) void gemm_mfma(
    const ushort_t* __restrict__ A, const ushort_t* __restrict__ Bt,
    const float* __restrict__ bias, float* __restrict__ Cf,
    ushort_t* __restrict__ Cb, int N)
{
    __shared__ ushort_t As[64*40];
    __shared__ ushort_t Bs[64*40];
    const int t = threadIdx.x;
    const int wave = t >> 6, lane = t & 63, m = lane & 15, quad = lane >> 4;
    const int rowBase = blockIdx.x * 64, colBase = blockIdx.y * 64;
    f32x4 acc[4];
    #pragma unroll
    for (int nt = 0; nt < 4; ++nt) acc[nt] = (f32x4){0.f,0.f,0.f,0.f};
    for (int ks = 0; ks < 6; ++ks) {
        __syncthreads();
        {   int r = t >> 2, seg = t & 3;
            *(uint4*)&As[r*40 + seg*8] = *(const uint4*)(A + (size_t)(rowBase + r)*192 + ks*32 + seg*8);
            *(uint4*)&Bs[r*40 + seg*8] = *(const uint4*)(Bt + (size_t)(colBase + r)*192 + ks*32 + seg*8);
        }
        __syncthreads();
        short8 a = *(const short8*)&As[(wave*16 + m)*40 + quad*8];
        #pragma unroll
        for (int nt = 0; nt < 4; ++nt) {
            short8 b = *(const short8*)&Bs[(nt*16 + m)*40 + quad*8];
            acc[nt] = __builtin_amdgcn_mfma_f32_16x16x32_bf16(a, b, acc[nt], 0, 0, 0);
        }
    }
    #pragma unroll
    for (int nt = 0; nt < 4; ++nt) {
        int col = colBase + nt*16 + m;
        float bv = bias ? bias[col] : 0.f;
        #pragma unroll
        for (int reg = 0; reg < 4; ++reg) {
            int row = rowBase + wave*16 + quad*4 + reg;
            float v = acc[nt][reg] + bv;
            if (Cf) Cf[(size_t)row*N + col] = v;
            else    Cb[(size_t)row*N + col] = f2bf(v);
        }
    }
}

// ---- K3a v2: keypoint attention via MFMA (8 points/block) + U assembly ----
__global__ __launch_bounds__(256) void k3a(
    const float* __restrict__ p, const float* __restrict__ kn,
    const float* __restrict__ deW1, const float* __restrict__ deB1,
    const float* __restrict__ deB2, const float* __restrict__ kpW,
    const float* __restrict__ gAW, const float* __restrict__ gAb,
    const float* __restrict__ gBW, const float* __restrict__ gBb,
    float* __restrict__ ws)
{
    __shared__ ushort_t fb[128*72];     // f rows bf16, K pad 64, stride 72
    __shared__ float kds[8][16];
    __shared__ float w1s[48], b1s[48];
    __shared__ float dfeat[8][192];
    ushort_t* ub = (ushort_t*)(ws + WS_UB);
    const int t = threadIdx.x;
    const int nb = blockIdx.x * 8;
    if (t < 48) { w1s[t] = deW1[t]; b1s[t] = deB1[t]; }
    if (t < 128) {
        int w = t >> 4, kp = t & 15;
        float dx = p[(nb+w)*3+0]-kn[kp*3+0];
        float dy = p[(nb+w)*3+1]-kn[kp*3+1];
        float dz = p[(nb+w)*3+2]-kn[kp*3+2];
        kds[w][kp] = sqrtf(dx*dx + dy*dy + dz*dz + 1e-12f);
    }
    __syncthreads();
    for (int e = t; e < 128*64; e += 256) {   // f = relu(kd*w1+b1), bf16 A tile
        int j = e >> 6, k = e & 63;
        float v = (k < 48) ? fmaxf(kds[j>>4][j&15]*w1s[k] + b1s[k], 0.f) : 0.f;
        fb[j*72 + k] = f2bf(v);
    }
    __syncthreads();
    const int wave = t >> 6, lane = t & 63, m = lane & 15, quad = lane >> 4;
    const ushort_t* dwt = (const ushort_t*)(ws + WS_DEW2T);
    short8 afr[2][2];
    #pragma unroll
    for (int mt = 0; mt < 2; ++mt)
        #pragma unroll
        for (int ks = 0; ks < 2; ++ks)
            afr[mt][ks] = *(const short8*)&fb[((wave*2 + mt)*16 + m)*72 + ks*32 + quad*8];
    float df[2][12][4];
    float sc[2][4];
    #pragma unroll
    for (int mt = 0; mt < 2; ++mt)
        #pragma unroll
        for (int reg = 0; reg < 4; ++reg) sc[mt][reg] = 0.f;
    for (int nt = 0; nt < 12; ++nt) {
        f32x4 acc0 = (f32x4){0.f,0.f,0.f,0.f};
        f32x4 acc1 = (f32x4){0.f,0.f,0.f,0.f};
        #pragma unroll
        for (int ks = 0; ks < 2; ++ks) {
            short8 b = *(const short8*)(dwt + ((size_t)(nt*16 + m)*64 + ks*32 + quad*8));
            acc0 = __builtin_amdgcn_mfma_f32_16x16x32_bf16(afr[0][ks], b, acc0, 0, 0, 0);
            acc1 = __builtin_amdgcn_mfma_f32_16x16x32_bf16(afr[1][ks], b, acc1, 0, 0, 0);
        }
        int col = nt*16 + m;
        float b2 = deB2[col], kw = kpW[col];
        #pragma unroll
        for (int reg = 0; reg < 4; ++reg) {
            float d0 = acc0[reg] + b2, d1 = acc1[reg] + b2;
            df[0][nt][reg] = d0; df[1][nt][reg] = d1;
            sc[0][reg] += d0*kw; sc[1][reg] += d1*kw;
        }
    }
    #pragma unroll
    for (int mt = 0; mt < 2; ++mt)     // reduce score over m lanes (width 16)
        #pragma unroll
        for (int reg = 0; reg < 4; ++reg) {
            float v = sc[mt][reg];
            v += __shfl_xor(v, 1, 16); v += __shfl_xor(v, 2, 16);
            v += __shfl_xor(v, 4, 16); v += __shfl_xor(v, 8, 16);
            sc[mt][reg] = v;
        }
    float wgt[2][4];
    #pragma unroll
    for (int mt = 0; mt < 2; ++mt) {   // softmax over kp = quad*4+reg (kpB const: dropped)
        float mx = fmaxf(fmaxf(sc[mt][0], sc[mt][1]), fmaxf(sc[mt][2], sc[mt][3]));
        mx = fmaxf(mx, __shfl_xor(mx, 16));
        mx = fmaxf(mx, __shfl_xor(mx, 32));
        float sm = 0.f;
        #pragma unroll
        for (int reg = 0; reg < 4; ++reg) { wgt[mt][reg] = expf(sc[mt][reg] - mx); sm += wgt[mt][reg]; }
        sm += __shfl_xor(sm, 16);
        sm += __shfl_xor(sm, 32);
        float inv = 1.f / sm;
        #pragma unroll
        for (int reg = 0; reg < 4; ++reg) wgt[mt][reg] *= inv;
    }
    for (int nt = 0; nt < 12; ++nt) {  // dfeat = attn-weighted kp-reduction
        int col = nt*16 + m;
        #pragma unroll
        for (int mt = 0; mt < 2; ++mt) {
            float s = 0.f;
            #pragma unroll
            for (int reg = 0; reg < 4; ++reg) s += wgt[mt][reg] * df[mt][nt][reg];
            s += __shfl_xor(s, 16);
            s += __shfl_xor(s, 32);
            if (quad == 0) dfeat[wave*2 + mt][col] = s;
        }
    }
    __syncthreads();
    if (t < DD) {                      // U assembly -> bf16 UB
        for (int w = 0; w < 8; ++w) {
            int n = nb + w;
            float uval = ws[WS_X1 + (size_t)n*DD + t] + gAb[t] + gBb[t]
                       + ws[WS_VOLV + t] + dfeat[w][t];
            uval += ws[WS_GDIS + n] * gBW[t];
            #pragma unroll
            for (int kk = 0; kk < 9; ++kk) uval += ws[WS_GEO9 + (size_t)n*9 + kk] * gAW[kk*DD + t];
            ub[(size_t)n*DD + t] = f2bf(uval);
        }
    }
}

// ---- K_attn_fused v3: 8 windows/block, 35.8KB LDS, rq+pv via MFMA ----
__global__ __launch_bounds__(256, 4) void k_attn_fused(
    const int* __restrict__ knn,
    const float* __restrict__ posB2,
    float* __restrict__ ws)
{
    __shared__ ushort_t rqs[8*6*192];   // bf16 rq (per i); later bf16 wsum
    __shared__ ushort_t qkb[8*192];     // bf16 q rows (i=0) / k rows (i=1)
    __shared__ float scb[8*192];        // scores sc[w][i*96+h*16+j]; later pv[w][t]
    __shared__ float dqk[8*96];         // dqk[w][h][j]
    __shared__ float attns[8*96];
    __shared__ float Xl[8][48];
    __shared__ int idxs[128];
    const int t = threadIdx.x;
    const int nb = blockIdx.x * 8;
    ushort_t* ctrb = (ushort_t*)(ws + WS_CTRB);
    const ushort_t* qkvb  = (const ushort_t*)(ws + WS_QKV);
    const ushort_t* w2b   = (const ushort_t*)(ws + WS_W2B);
    const ushort_t* w2t2b = (const ushort_t*)(ws + WS_W2T2B);
    const ushort_t* w1t   = (const ushort_t*)(ws + WS_W1T);
    if (t < 128) idxs[t] = knn[(nb + (t >> 4))*NS + (t & 15)];
    for (int e = t; e < 384; e += 256) {
        int w = e/48, k = e%48;
        Xl[w][k] = ws[WS_KNN + (size_t)(nb+w)*48 + k];
    }
    __syncthreads();
    const int wave = t >> 6, lane = t & 63, m = lane & 15, quad = lane >> 4;
    // pos A-fragments in registers: pos[j][k] = Xl[w][k] - Xl[w][(j&15)*3 + k%3]
    short8 afr[2][2];
    #pragma unroll
    for (int mt = 0; mt < 2; ++mt) {
        const int w = wave*2 + mt;
        #pragma unroll
        for (int ks = 0; ks < 2; ++ks) {
            short8 v;
            #pragma unroll
            for (int e = 0; e < 8; ++e) {
                const int k = ks*32 + quad*8 + e;
                float f = (k < 48) ? (Xl[w][k] - Xl[w][m*3 + (k % 3)]) : 0.f;
                v[e] = (short)f2bf(f);
            }
            afr[mt][ks] = v;
        }
    }
    // ---- i = 0,1: rq via MFMA + H MFMA + fused contraction -> scb ----
    for (int i = 0; i < 2; ++i) {
        __syncthreads();   // prior rqs/qkb readers done
        for (int e = t; e < 8*192; e += 256) {
            int w = e/192, c = e%192;
            qkb[e] = qkvb[(size_t)idxs[w*16]*576 + i*192 + c];
        }
        __syncthreads();
        // rq[w][h][kk] = sum_c qk[w][c_h] * posW2[i][kk][c_h]  (MFMA, M=8 of 16)
        #pragma unroll
        for (int hh = 0; hh < 6; ++hh) {
            short8 aq = *(const short8*)&qkb[(m & 7)*192 + hh*32 + quad*8];
            #pragma unroll
            for (int l = 0; l < 3; ++l) {
                const int nt = wave*3 + l;
                short8 b = *(const short8*)(w2b + (size_t)i*36864
                            + (size_t)(nt*16 + m)*192 + hh*32 + quad*8);
                f32x4 acc = (f32x4){0.f,0.f,0.f,0.f};
                acc = __builtin_amdgcn_mfma_f32_16x16x32_bf16(aq, b, acc, 0, 0, 0);
                if (quad < 2) {
                    #pragma unroll
                    for (int reg = 0; reg < 4; ++reg) {
                        int w = quad*4 + reg;
                        rqs[(w*6 + hh)*192 + nt*16 + m] = f2bf(acc[reg]);
                    }
                }
            }
        }
        __syncthreads();   // rqs ready (cross-wave)
        float s[48];       // [mt(2)][reg(4)][h(6)]
        #pragma unroll
        for (int e = 0; e < 48; ++e) s[e] = 0.f;
        for (int nt = 0; nt < 12; ++nt) {
            f32x4 acc0 = (f32x4){0.f,0.f,0.f,0.f};
            f32x4 acc1 = (f32x4){0.f,0.f,0.f,0.f};
            #pragma unroll
            for (int ks = 0; ks < 2; ++ks) {
                short8 b = *(const short8*)(w1t + ((size_t)(i*192 + nt*16 + m)*64 + ks*32 + quad*8));
                acc0 = __builtin_amdgcn_mfma_f32_16x16x32_bf16(afr[0][ks], b, acc0, 0, 0, 0);
                acc1 = __builtin_amdgcn_mfma_f32_16x16x32_bf16(afr[1][ks], b, acc1, 0, 0, 0);
            }
            int kk = nt*16 + m;
            float as = ws[WS_AB + i*DD + kk];
            float bb = ws[WS_AB + 576 + i*DD + kk];
            float h0[4], h1[4];
            #pragma unroll
            for (int reg = 0; reg < 4; ++reg) {
                h0[reg] = fmaxf(acc0[reg]*as + bb, 0.f);
                h1[reg] = fmaxf(acc1[reg]*as + bb, 0.f);
            }
            #pragma unroll
            for (int h = 0; h < 6; ++h) {
                float r0 = bf2f(rqs[((wave*2 + 0)*6 + h)*192 + kk]);
                float r1 = bf2f(rqs[((wave*2 + 1)*6 + h)*192 + kk]);
                #pragma unroll
                for (int reg = 0; reg < 4; ++reg) {
                    s[reg*6 + h]      += h0[reg]*r0;
                    s[24 + reg*6 + h] += h1[reg]*r1;
                }
            }
        }
        #pragma unroll
        for (int e = 0; e < 48; ++e) {
            float v = s[e];
            v += __shfl_xor(v, 1, 16); v += __shfl_xor(v, 2, 16);
            v += __shfl_xor(v, 4, 16); v += __shfl_xor(v, 8, 16);
            s[e] = v;
        }
        if (m == 0) {
            #pragma unroll
            for (int mt = 0; mt < 2; ++mt)
                #pragma unroll
                for (int reg = 0; reg < 4; ++reg) {
                    int w = wave*2 + mt, j = quad*4 + reg;
                    #pragma unroll
                    for (int h = 0; h < 6; ++h)
                        scb[w*192 + i*96 + h*16 + j] = s[mt*24 + reg*6 + h];
                }
        }
    }
    // ---- dqk dots: thread -> (w, j, half); bf16 rows ----
    {
        const int w = t >> 5, r = t & 31, j = r >> 1, half = r & 1;
        const ushort_t* krow = qkvb + (size_t)idxs[w*16 + j]*576 + 192 + half*96;
        const ushort_t* qrow = qkvb + (size_t)idxs[w*16]*576 + half*96;
        float hd[3] = {0.f, 0.f, 0.f};
        #pragma unroll
        for (int q = 0; q < 12; ++q) {
            uint4 kv = *(const uint4*)(krow + q*8);
            uint4 qv = *(const uint4*)(qrow + q*8);
            float sv = 0.f;
            #pragma unroll
            for (int d = 0; d < 4; ++d) {
                unsigned int ku = (&kv.x)[d], qu = (&qv.x)[d];
                sv += __uint_as_float(ku << 16) * __uint_as_float(qu << 16);
                sv += __uint_as_float(ku & 0xffff0000u) * __uint_as_float(qu & 0xffff0000u);
            }
            hd[q >> 2] += sv;
        }
        dqk[w*96 + (half*3+0)*16 + j] = hd[0];
        dqk[w*96 + (half*3+1)*16 + j] = hd[1];
        dqk[w*96 + (half*3+2)*16 + j] = hd[2];
    }
    __syncthreads();   // dqk+scb ready; also all rqs reads (i=1) done
    // ---- softmax over j per (w,h) ----
    {
        const float scale = 0.17677669529663687f;  // 32^-0.5
        #pragma unroll
        for (int c = 0; c < 3; ++c) {
            int e = c*256 + t;
            int row = e >> 4, j = e & 15, w = row / 6, h = row % 6;
            float z = (dqk[e] + scb[w*192 + h*16 + j] + scb[w*192 + 96 + h*16 + j]) * scale;
            float mx = z;
            #pragma unroll
            for (int off = 1; off < 16; off <<= 1) mx = fmaxf(mx, __shfl_xor(mx, off, 16));
            float ex = expf(z - mx);
            float sm = ex;
            #pragma unroll
            for (int off = 1; off < 16; off <<= 1) sm += __shfl_xor(sm, off, 16);
            attns[w*96 + h*16 + j] = ex / sm;
        }
    }
    __syncthreads();   // attns ready (scb free after this point)
    // ---- ctr1 = attn @ v (bf16 V rows) ----
    float ctr1[8];
    if (t < DD) {
        const int h = t >> 5;
        #pragma unroll
        for (int w = 0; w < 8; ++w) {
            float sv = 0.f;
            #pragma unroll
            for (int j = 0; j < NS; ++j)
                sv += attns[w*96 + h*16 + j] * bf2f(qkvb[(size_t)idxs[w*16 + j]*576 + 384 + t]);
            ctr1[w] = sv;
        }
    }
    // ---- H2 MFMA + attn-weighted reduce -> bf16 wsum (rqs region) ----
    {
        ushort_t* wsum = rqs;
        const int w0 = wave*2, w1 = wave*2 + 1;
        for (int nt = 0; nt < 12; ++nt) {
            f32x4 acc0 = (f32x4){0.f,0.f,0.f,0.f};
            f32x4 acc1 = (f32x4){0.f,0.f,0.f,0.f};
            #pragma unroll
            for (int ks = 0; ks < 2; ++ks) {
                short8 b = *(const short8*)(w1t + ((size_t)(2*192 + nt*16 + m)*64 + ks*32 + quad*8));
                acc0 = __builtin_amdgcn_mfma_f32_16x16x32_bf16(afr[0][ks], b, acc0, 0, 0, 0);
                acc1 = __builtin_amdgcn_mfma_f32_16x16x32_bf16(afr[1][ks], b, acc1, 0, 0, 0);
            }
            int kk = nt*16 + m;
            float as = ws[WS_AB + 2*DD + kk];
            float bb = ws[WS_AB + 576 + 2*DD + kk];
            float h0[4], h1[4];
            #pragma unroll
            for (int reg = 0; reg < 4; ++reg) {
                h0[reg] = fmaxf(acc0[reg]*as + bb, 0.f);
                h1[reg] = fmaxf(acc1[reg]*as + bb, 0.f);
            }
            #pragma unroll
            for (int h = 0; h < 6; ++h) {
                float p0 = 0.f, p1 = 0.f;
                #pragma unroll
                for (int reg = 0; reg < 4; ++reg) {
                    int j = quad*4 + reg;
                    p0 += attns[w0*96 + h*16 + j] * h0[reg];
                    p1 += attns[w1*96 + h*16 + j] * h1[reg];
                }
                p0 += __shfl_xor(p0, 16); p0 += __shfl_xor(p0, 32);
                p1 += __shfl_xor(p1, 16); p1 += __shfl_xor(p1, 32);
                if (quad == 0) {
                    wsum[(w0*6 + h)*192 + kk] = f2bf(p0);
                    wsum[(w1*6 + h)*192 + kk] = f2bf(p1);
                }
            }
        }
    }
    __syncthreads();   // wsum ready
    // ---- pv via MFMA: pv[w][t] = sum_k wsum[w][h(t)][k] * posW2[2][k][t] -> scb ----
    {
        const ushort_t* wsum = rqs;
        #pragma unroll
        for (int l = 0; l < 3; ++l) {
            const int nt = wave*3 + l;       // output t-tile 0..11
            const int h = nt >> 1;           // head of this t-tile
            f32x4 acc = (f32x4){0.f,0.f,0.f,0.f};
            #pragma unroll
            for (int ks = 0; ks < 6; ++ks) {
                short8 a = *(const short8*)&wsum[((m & 7)*6 + h)*192 + ks*32 + quad*8];
                short8 b = *(const short8*)(w2t2b + (size_t)(nt*16 + m)*192 + ks*32 + quad*8);
                acc = __builtin_amdgcn_mfma_f32_16x16x32_bf16(a, b, acc, 0, 0, 0);
            }
            if (quad < 2) {
                #pragma unroll
                for (int reg = 0; reg < 4; ++reg) {
                    int w = quad*4 + reg;
                    scb[w*192 + nt*16 + m] = acc[reg];
                }
            }
        }
    }
    __syncthreads();   // pv ready
    // ---- CTR = ctr1 + pv + b2 ----
    if (t < DD) {
        float b2 = posB2[2*DD + t];
        #pragma unroll
        for (int w = 0; w < 8; ++w)
            ctrb[(size_t)(nb+w)*DD + t] = f2bf(ctr1[w] + scb[w*192 + t] + b2);
    }
}

extern "C" void kernel_launch(void* const* d_in, const int* in_sizes, int n_in,
                              void* d_out, int out_size, void* d_ws, size_t ws_size,
                              hipStream_t stream)
{
    const float* p     = (const float*)d_in[0];
    const float* x     = (const float*)d_in[1];
    const int*   knn   = (const int*)  d_in[2];
    const float* Wqkv  = (const float*)d_in[3];
    const float* Wproj = (const float*)d_in[4];
    const float* bproj = (const float*)d_in[5];
    const float* propW = (const float*)d_in[6];
    const float* propB = (const float*)d_in[7];
    const float* gAW   = (const float*)d_in[8];
    const float* gAb   = (const float*)d_in[9];
    const float* gBW   = (const float*)d_in[10];
    const float* gBb   = (const float*)d_in[11];
    const float* gCW   = (const float*)d_in[12];
    const float* gCb   = (const float*)d_in[13];
    const float* posW1 = (const float*)d_in[14];
    const float* posB1 = (const float*)d_in[15];
    const float* gamma = (const float*)d_in[16];
    const float* beta  = (const float*)d_in[17];
    const float* posW2 = (const float*)d_in[18];
    const float* posB2 = (const float*)d_in[19];
    const float* kn    = (const float*)d_in[20];
    const float* deW1  = (const float*)d_in[21];
    const float* deB1  = (const float*)d_in[22];
    const float* deW2  = (const float*)d_in[23];
    const float* deB2  = (const float*)d_in[24];
    const float* kpW   = (const float*)d_in[25];
    const float* kpB   = (const float*)d_in[26];
    const float* fusW  = (const float*)d_in[27];
    const float* fusB  = (const float*)d_in[28];
    float* ws   = (float*)d_ws;
    float* outp = (float*)d_out;
    (void)kpB;  // constant shift inside softmax: invariant, dropped

    hipLaunchKernelGGL(k_init, dim3(10), dim3(256), 0, stream, ws);
    hipLaunchKernelGGL(k_prep, dim3(1488), dim3(256), 0, stream,
                       propW, Wqkv, fusW, Wproj, posW1, deW2, posW2, ws);
    hipLaunchKernelGGL(k_castx, dim3(NP*DD/256), dim3(256), 0, stream, x, ws);
    hipLaunchKernelGGL(k1a_geom, dim3(NP/16), dim3(256), 0, stream, p, knn, ws);
    hipLaunchKernelGGL(k1b_stats, dim3(NP/128), dim3(256), 0, stream, ws);
    hipLaunchKernelGGL(k2_fold, dim3(3), dim3(256), 0, stream,
                       posW1, posB1, gamma, beta, gCW, gCb, ws);
    hipLaunchKernelGGL(k_prop_mfma, dim3(MTOT/64), dim3(256), 0, stream,
                       x, knn, propW, propB, ws);
    hipLaunchKernelGGL(k3a, dim3(NP/8), dim3(256), 0, stream,
                       p, kn, deW1, deB1, deB2, kpW, gAW, gAb, gBW, gBb, ws);
    // X2B = bf16(UB @ fusW + fusB)
    hipLaunchKernelGGL(gemm_mfma, dim3(NP/64, 3), dim3(256), 0, stream,
                       (const ushort_t*)(ws + WS_UB), (const ushort_t*)(ws + WS_FUSWT),
                       fusB, (float*)nullptr, (ushort_t*)(ws + WS_X2B), DD);
    // QKV = bf16(X2B @ Wqkv)
    hipLaunchKernelGGL(gemm_mfma, dim3(NP/64, 9), dim3(256), 0, stream,
                       (const ushort_t*)(ws + WS_X2B), (const ushort_t*)(ws + WS_QKVT),
                       (const float*)nullptr, (float*)nullptr,
                       (ushort_t*)(ws + WS_QKV), 576);
    hipLaunchKernelGGL(k_attn_fused, dim3(NP/8), dim3(256), 0, stream,
                       knn, posB2, ws);
    // OUT = CTRB @ Wproj + bproj (fp32 out)
    hipLaunchKernelGGL(gemm_mfma, dim3(NP/64, 3), dim3(256), 0, stream,
                       (const ushort_t*)(ws + WS_CTRB), (const ushort_t*)(ws + WS_PROJWT),
                       bproj, outp, (ushort_t*)nullptr, DD);
}